// Round 1
// baseline (1356.998 us; speedup 1.0000x reference)
//
#include <hip/hip_runtime.h>
#include <stdint.h>

// SpatiotemporalAttention: B=16 W=128 S=16 D=768 H=12 HD=64
// Pipeline (all token-order (b,w,s,d)):
//  LN1 -> GEMM qkv -> spatial attn (S=16, no mask) -> GEMM +resid(x f32) -> xs2
//  LN2 -> GEMM tqkv -> temporal attn (W=128, causal, RoPE) -> GEMM +resid -> xt2
//  LN3 -> GEMM f1+gelu -> GEMM f2 +resid -> d_out (f32)
// All GEMMs bf16 MFMA 16x16x32, 128x128 tile, BK=32, global_load_lds w=16 (m97 structure).

#define NB 16
#define NW 128
#define NS 16
#define ND 768
#define NH 12
#define NTOK 32768

typedef __attribute__((ext_vector_type(8))) short short8;
typedef __attribute__((ext_vector_type(4))) float f32x4;

__device__ __forceinline__ float blo(unsigned v){ return __builtin_bit_cast(float, v << 16); }
__device__ __forceinline__ float bhi(unsigned v){ return __builtin_bit_cast(float, v & 0xffff0000u); }
__device__ __forceinline__ float bus(unsigned short u){ return __builtin_bit_cast(float, ((unsigned)u) << 16); }
__device__ __forceinline__ unsigned short f2b(float f){
  unsigned u = __builtin_bit_cast(unsigned, f);
  u += 0x7fffu + ((u >> 16) & 1u);
  return (unsigned short)(u >> 16);
}
__device__ __forceinline__ void gld_lds16(const void* g, void* l){
  __builtin_amdgcn_global_load_lds((const __attribute__((address_space(1))) void*)g,
                                   (__attribute__((address_space(3))) void*)l, 16, 0, 0);
}

// ---------------- weight convert f32 -> bf16 (n multiple of 4) ----------------
__global__ __launch_bounds__(256) void convert_k(const float* __restrict__ in,
                                                 unsigned short* __restrict__ out, int n4){
  int i = blockIdx.x * 256 + threadIdx.x;
  int stride = gridDim.x * 256;
  for (; i < n4; i += stride){
    float4 v = ((const float4*)in)[i];
    unsigned lo = (unsigned)f2b(v.x) | ((unsigned)f2b(v.y) << 16);
    unsigned hi = (unsigned)f2b(v.z) | ((unsigned)f2b(v.w) << 16);
    ((uint2*)out)[i] = make_uint2(lo, hi);
  }
}

__global__ __launch_bounds__(256) void concat3_k(const float* __restrict__ a, const float* __restrict__ b,
                                                 const float* __restrict__ c, float* __restrict__ o){
  int i = blockIdx.x * 256 + threadIdx.x;
  if (i < 768){ o[i] = a[i]; o[768 + i] = b[i]; o[1536 + i] = c[i]; }
}

// rope table [128 pos][32 pair] -> (cos, sin)
__global__ __launch_bounds__(256) void rope_k(float* __restrict__ tab){
  int i = blockIdx.x * 256 + threadIdx.x;
  if (i < 128 * 32){
    int w = i >> 5, p = i & 31;
    float inv = powf(10000.0f, -((float)(2 * p)) / 64.0f);
    float ang = (float)w * inv;
    tab[i * 2] = cosf(ang);
    tab[i * 2 + 1] = sinf(ang);
  }
}

// ---------------- LayerNorm: one block per 768-row, out bf16 ----------------
template<int INF32>
__global__ __launch_bounds__(256) void ln_k(const void* __restrict__ xin, const float* __restrict__ g,
                                            const float* __restrict__ bt, unsigned short* __restrict__ out){
  const int row = blockIdx.x;
  const int t = threadIdx.x;
  const float* xf = (const float*)xin;
  const unsigned short* xb = (const unsigned short*)xin;
  float v[3];
#pragma unroll
  for (int i = 0; i < 3; ++i){
    int j = t + i * 256;
    v[i] = INF32 ? xf[(size_t)row * 768 + j] : bus(xb[(size_t)row * 768 + j]);
  }
  float s = v[0] + v[1] + v[2];
  float ss = v[0]*v[0] + v[1]*v[1] + v[2]*v[2];
#pragma unroll
  for (int o = 1; o < 64; o <<= 1){ s += __shfl_xor(s, o, 64); ss += __shfl_xor(ss, o, 64); }
  __shared__ float red[8];
  int w = t >> 6;
  if ((t & 63) == 0){ red[w*2] = s; red[w*2+1] = ss; }
  __syncthreads();
  s = red[0] + red[2] + red[4] + red[6];
  ss = red[1] + red[3] + red[5] + red[7];
  float mean = s * (1.0f / 768.0f);
  float var = ss * (1.0f / 768.0f) - mean * mean;
  float rstd = rsqrtf(var + 1e-5f);
#pragma unroll
  for (int i = 0; i < 3; ++i){
    int j = t + i * 256;
    out[(size_t)row * 768 + j] = f2b((v[i] - mean) * rstd * g[j] + bt[j]);
  }
}

// ---------------- GEMM: out[n][m] = sum_k A[n][k]*Bw[m][k] (+bias,+resid,gelu) ----------------
// MODE 0: out bf16 = acc+bias          1: out bf16 = gelu(acc+bias)
// MODE 2: out bf16 = acc+bias+resid(f32)   3: out bf16 = acc+bias+resid(bf16)
// MODE 4: out f32  = acc+bias+resid(bf16)
template<int MODE>
__global__ __launch_bounds__(256) void gemm_k(const unsigned short* __restrict__ A,
                                              const unsigned short* __restrict__ Bw,
                                              const float* __restrict__ bias,
                                              const void* __restrict__ resid,
                                              void* __restrict__ outp, int K, int M){
  __shared__ unsigned short As[128 * 32];
  __shared__ unsigned short Bs[128 * 32];
  const int t = threadIdx.x;
  const int lane = t & 63, w = t >> 6;
  const int lhi = lane >> 4, llo = lane & 15;
  const int row0 = blockIdx.x << 7, col0 = blockIdx.y << 7;
  const int wm = w >> 1, wn = w & 1;

  f32x4 acc[4][4];
#pragma unroll
  for (int i = 0; i < 4; ++i)
#pragma unroll
    for (int j = 0; j < 4; ++j) acc[i][j] = f32x4{0.f, 0.f, 0.f, 0.f};

  // staging: LDS linear [row][32 bf16]; 16B slot s -> row=s>>2, koff=(s&3)*8
  const int s0 = (w << 6) + lane;
  const int ra0 = s0 >> 2, ka0 = (s0 & 3) << 3;
  const int ra1 = (s0 + 256) >> 2, ka1 = ((s0 + 256) & 3) << 3;
  const unsigned short* gA0 = A + (size_t)(row0 + ra0) * K + ka0;
  const unsigned short* gA1 = A + (size_t)(row0 + ra1) * K + ka1;
  const unsigned short* gB0 = Bw + (size_t)(col0 + ra0) * K + ka0;
  const unsigned short* gB1 = Bw + (size_t)(col0 + ra1) * K + ka1;
  unsigned short* lA0 = &As[(w << 6) * 8];
  unsigned short* lA1 = &As[((w << 6) + 256) * 8];
  unsigned short* lB0 = &Bs[(w << 6) * 8];
  unsigned short* lB1 = &Bs[((w << 6) + 256) * 8];

  for (int k0 = 0; k0 < K; k0 += 32){
    gld_lds16(gA0 + k0, lA0);
    gld_lds16(gA1 + k0, lA1);
    gld_lds16(gB0 + k0, lB0);
    gld_lds16(gB1 + k0, lB1);
    __syncthreads();   // compiler drains vmcnt(0) before barrier
    short8 a[4], b[4];
#pragma unroll
    for (int f = 0; f < 4; ++f){
      a[f] = *(const short8*)&As[((wm << 6) + (f << 4) + llo) * 32 + (lhi << 3)];
      b[f] = *(const short8*)&Bs[((wn << 6) + (f << 4) + llo) * 32 + (lhi << 3)];
    }
#pragma unroll
    for (int i = 0; i < 4; ++i)
#pragma unroll
      for (int j = 0; j < 4; ++j)
        acc[i][j] = __builtin_amdgcn_mfma_f32_16x16x32_bf16(a[i], b[j], acc[i][j], 0, 0, 0);
    __syncthreads();
  }

  const unsigned short* resb = (const unsigned short*)resid;
  const float* resf = (const float*)resid;
#pragma unroll
  for (int i = 0; i < 4; ++i){
    const int rbase = row0 + (wm << 6) + (i << 4) + (lhi << 2);
#pragma unroll
    for (int j = 0; j < 4; ++j){
      const int c = col0 + (wn << 6) + (j << 4) + llo;
      const float bv = bias[c];
#pragma unroll
      for (int r = 0; r < 4; ++r){
        const size_t off = (size_t)(rbase + r) * M + c;
        float v = acc[i][j][r] + bv;
        if (MODE == 0){
          ((unsigned short*)outp)[off] = f2b(v);
        } else if (MODE == 1){
          float ge = 0.5f * v * (1.0f + erff(v * 0.70710678118654752f));
          ((unsigned short*)outp)[off] = f2b(ge);
        } else if (MODE == 2){
          ((unsigned short*)outp)[off] = f2b(v + resf[off]);
        } else if (MODE == 3){
          ((unsigned short*)outp)[off] = f2b(v + bus(resb[off]));
        } else {
          ((float*)outp)[off] = v + bus(resb[off]);
        }
      }
    }
  }
}

// ---------------- spatial attention: block = (bw, h), S=16, no mask ----------------
__global__ __launch_bounds__(256) void sattn_k(const unsigned short* __restrict__ qkv,
                                               unsigned short* __restrict__ o){
  const int bw = blockIdx.x, h = blockIdx.y;
  const int t = threadIdx.x;
  __shared__ unsigned short qh[16 * 68], kh[16 * 68], vh[16 * 68]; // +4 pad vs bank conflicts
  __shared__ float pl[16 * 17];
  const int row = t >> 4, c4 = t & 15;
  const size_t base = ((size_t)(bw * 16 + row)) * 2304 + h * 64 + c4 * 4;
  *(uint2*)&qh[row * 68 + c4 * 4] = *(const uint2*)&qkv[base];
  *(uint2*)&kh[row * 68 + c4 * 4] = *(const uint2*)&qkv[base + 768];
  *(uint2*)&vh[row * 68 + c4 * 4] = *(const uint2*)&qkv[base + 1536];
  __syncthreads();

  const int q = row, k = c4;
  float s = 0.f;
#pragma unroll
  for (int c = 0; c < 16; ++c){
    uint2 qv = *(const uint2*)&qh[q * 68 + c * 4];
    uint2 kv = *(const uint2*)&kh[k * 68 + c * 4];
    s += blo(qv.x) * blo(kv.x) + bhi(qv.x) * bhi(kv.x);
    s += blo(qv.y) * blo(kv.y) + bhi(qv.y) * bhi(kv.y);
  }
  s *= 0.125f;
  float m = s;
#pragma unroll
  for (int off = 1; off < 16; off <<= 1) m = fmaxf(m, __shfl_xor(m, off, 64));
  float p = __expf(s - m);
  float su = p;
#pragma unroll
  for (int off = 1; off < 16; off <<= 1) su += __shfl_xor(su, off, 64);
  pl[q * 17 + k] = p / su;
  __syncthreads();

  float o0 = 0.f, o1 = 0.f, o2 = 0.f, o3 = 0.f;
#pragma unroll
  for (int kk = 0; kk < 16; ++kk){
    float pw = pl[q * 17 + kk];
    uint2 vv = *(const uint2*)&vh[kk * 68 + c4 * 4];
    o0 += pw * blo(vv.x); o1 += pw * bhi(vv.x);
    o2 += pw * blo(vv.y); o3 += pw * bhi(vv.y);
  }
  const size_t ob = ((size_t)(bw * 16 + q)) * 768 + h * 64 + c4 * 4;
  unsigned r0 = (unsigned)f2b(o0) | ((unsigned)f2b(o1) << 16);
  unsigned r1 = (unsigned)f2b(o2) | ((unsigned)f2b(o3) << 16);
  *(uint2*)&o[ob] = make_uint2(r0, r1);
}

// ---------------- temporal attention: block = (b*16+s, h), W=128, causal, RoPE ----------------
// MFMA: S^T = mfma(K,Q) so P-quads (4 consecutive k) pack to ds_write_b64 at P[q][k].
// LDS XOR-swizzle (T2): byte ^= (row&7)<<4 on Qs/Ks/Vt/P (both write and read sides).
__global__ __launch_bounds__(256) void tattn_k(const unsigned short* __restrict__ qkv,
                                               const float* __restrict__ rope,
                                               unsigned short* __restrict__ o){
  const int bs = blockIdx.x, h = blockIdx.y;
  const int b = bs >> 4, s = bs & 15;
  const int t = threadIdx.x, lane = t & 63, w = t >> 6;
  const int lhi = lane >> 4, llo = lane & 15;
  __shared__ unsigned short Qs[128 * 64];   // [w][d] rows 128B, swizzled
  __shared__ unsigned short Ks[128 * 64];
  __shared__ unsigned short Vt[64 * 128];   // [d][k] rows 256B, swizzled
  __shared__ unsigned short P[128 * 128];   // [q][k] rows 256B, swizzled

  // ---- stage Q,K (RoPE) + V transposed ----
  {
    const int r = t >> 1;
    const int dbase = (t & 1) * 32;
    const size_t tokb = ((size_t)((b * 128 + r) * 16 + s)) * 2304 + h * 64;
    const float2* rp = (const float2*)rope;
#pragma unroll
    for (int mch = 0; mch < 4; ++mch){
      const int d0 = dbase + mch * 8;
      uint4 qv = *(const uint4*)&qkv[tokb + d0];
      uint4 kv = *(const uint4*)&qkv[tokb + 768 + d0];
      uint4 vv = *(const uint4*)&qkv[tokb + 1536 + d0];
      unsigned qin[4] = {qv.x, qv.y, qv.z, qv.w};
      unsigned kin[4] = {kv.x, kv.y, kv.z, kv.w};
      unsigned qo[4], ko[4];
#pragma unroll
      for (int j = 0; j < 4; ++j){
        float2 cssn = rp[r * 32 + (d0 >> 1) + j];
        float cs = cssn.x, sn = cssn.y;
        float qe = blo(qin[j]), qd = bhi(qin[j]);
        float ke = blo(kin[j]), kd = bhi(kin[j]);
        qo[j] = (unsigned)f2b(qe * cs - qd * sn) | ((unsigned)f2b(qe * sn + qd * cs) << 16);
        ko[j] = (unsigned)f2b(ke * cs - kd * sn) | ((unsigned)f2b(ke * sn + kd * cs) << 16);
      }
      const int byq = r * 128 + ((d0 * 2) ^ ((r & 7) << 4));
      *(uint4*)((char*)Qs + byq) = make_uint4(qo[0], qo[1], qo[2], qo[3]);
      *(uint4*)((char*)Ks + byq) = make_uint4(ko[0], ko[1], ko[2], ko[3]);
      unsigned vin[4] = {vv.x, vv.y, vv.z, vv.w};
#pragma unroll
      for (int j = 0; j < 8; ++j){
        const int d = d0 + j;
        unsigned short val = (j & 1) ? (unsigned short)(vin[j >> 1] >> 16)
                                     : (unsigned short)(vin[j >> 1] & 0xffffu);
        *(unsigned short*)((char*)Vt + d * 256 + ((r * 2) ^ ((d & 7) << 4))) = val;
      }
    }
  }
  __syncthreads();

  // ---- QK^T (transposed: rows=k, cols=q) ----
  const int qbase = w * 32;
  f32x4 st[8][2];
#pragma unroll
  for (int i = 0; i < 8; ++i){ st[i][0] = f32x4{0.f,0.f,0.f,0.f}; st[i][1] = f32x4{0.f,0.f,0.f,0.f}; }
#pragma unroll
  for (int kd = 0; kd < 2; ++kd){
    short8 bq[2];
#pragma unroll
    for (int fq = 0; fq < 2; ++fq){
      const int qr = qbase + fq * 16 + llo;
      bq[fq] = *(const short8*)((const char*)Qs + qr * 128 + ((kd * 64 + lhi * 16) ^ ((qr & 7) << 4)));
    }
#pragma unroll
    for (int fk = 0; fk < 8; ++fk){
      const int kr = fk * 16 + llo;
      short8 ak = *(const short8*)((const char*)Ks + kr * 128 + ((kd * 64 + lhi * 16) ^ ((kr & 7) << 4)));
      st[fk][0] = __builtin_amdgcn_mfma_f32_16x16x32_bf16(ak, bq[0], st[fk][0], 0, 0, 0);
      st[fk][1] = __builtin_amdgcn_mfma_f32_16x16x32_bf16(ak, bq[1], st[fk][1], 0, 0, 0);
    }
  }

  // ---- softmax (cols=q are lane-local llo; rows=k across regs + lane groups) ----
#pragma unroll
  for (int fq = 0; fq < 2; ++fq){
    const int qg = qbase + fq * 16 + llo;
    float m = -1e30f;
#pragma unroll
    for (int fk = 0; fk < 8; ++fk)
#pragma unroll
      for (int rr = 0; rr < 4; ++rr){
        const int kg = fk * 16 + lhi * 4 + rr;
        float sv = (kg <= qg) ? st[fk][fq][rr] : -1e30f;
        st[fk][fq][rr] = sv;
        m = fmaxf(m, sv);
      }
    m = fmaxf(m, __shfl_xor(m, 16, 64));
    m = fmaxf(m, __shfl_xor(m, 32, 64));
    float su = 0.f;
#pragma unroll
    for (int fk = 0; fk < 8; ++fk)
#pragma unroll
      for (int rr = 0; rr < 4; ++rr){
        float p = __expf((st[fk][fq][rr] - m) * 0.125f);
        st[fk][fq][rr] = p;
        su += p;
      }
    su += __shfl_xor(su, 16, 64);
    su += __shfl_xor(su, 32, 64);
    const float rs = 1.0f / su;
#pragma unroll
    for (int fk = 0; fk < 8; ++fk){
      const int kk = fk * 16 + lhi * 4;
      unsigned lo = (unsigned)f2b(st[fk][fq][0] * rs) | ((unsigned)f2b(st[fk][fq][1] * rs) << 16);
      unsigned hi = (unsigned)f2b(st[fk][fq][2] * rs) | ((unsigned)f2b(st[fk][fq][3] * rs) << 16);
      *(uint2*)((char*)P + qg * 256 + ((kk * 2) ^ ((qg & 7) << 4))) = make_uint2(lo, hi);
    }
  }
  __syncthreads();

  // ---- PV: O[q][d] = sum_k P[q][k] * Vt[d][k] ----
  f32x4 oacc[2][4];
#pragma unroll
  for (int i = 0; i < 2; ++i)
#pragma unroll
    for (int j = 0; j < 4; ++j) oacc[i][j] = f32x4{0.f,0.f,0.f,0.f};
#pragma unroll
  for (int ks = 0; ks < 4; ++ks){
    short8 pa[2];
#pragma unroll
    for (int fq = 0; fq < 2; ++fq){
      const int qr = qbase + fq * 16 + llo;
      pa[fq] = *(const short8*)((const char*)P + qr * 256 + ((ks * 64 + lhi * 16) ^ ((qr & 7) << 4)));
    }
#pragma unroll
    for (int fd = 0; fd < 4; ++fd){
      const int dr = fd * 16 + llo;
      short8 vb = *(const short8*)((const char*)Vt + dr * 256 + ((ks * 64 + lhi * 16) ^ ((dr & 7) << 4)));
      oacc[0][fd] = __builtin_amdgcn_mfma_f32_16x16x32_bf16(pa[0], vb, oacc[0][fd], 0, 0, 0);
      oacc[1][fd] = __builtin_amdgcn_mfma_f32_16x16x32_bf16(pa[1], vb, oacc[1][fd], 0, 0, 0);
    }
  }

#pragma unroll
  for (int fq = 0; fq < 2; ++fq)
#pragma unroll
    for (int fd = 0; fd < 4; ++fd)
#pragma unroll
      for (int rr = 0; rr < 4; ++rr){
        const int qg = qbase + fq * 16 + lhi * 4 + rr;
        const int d = fd * 16 + llo;
        const size_t ob = ((size_t)((b * 128 + qg) * 16 + s)) * 768 + h * 64 + d;
        o[ob] = f2b(oacc[fq][fd][rr]);
      }
}

__global__ __launch_bounds__(256) void sentinel_k(float* out){
  if (blockIdx.x == 0 && threadIdx.x == 0) out[0] = 12345.0f;
}

// ---------------- launch ----------------
extern "C" void kernel_launch(void* const* d_in, const int* in_sizes, int n_in,
                              void* d_out, int out_size, void* d_ws, size_t ws_size,
                              hipStream_t stream){
  const float* x       = (const float*)d_in[0];
  const float* sn_g    = (const float*)d_in[2];
  const float* sn_b    = (const float*)d_in[3];
  const float* sa_in_w = (const float*)d_in[4];
  const float* sa_in_b = (const float*)d_in[5];
  const float* sa_out_w= (const float*)d_in[6];
  const float* sa_out_b= (const float*)d_in[7];
  const float* tn_g    = (const float*)d_in[8];
  const float* tn_b    = (const float*)d_in[9];
  const float* tq_w    = (const float*)d_in[10];
  const float* tq_b    = (const float*)d_in[11];
  const float* tk_w    = (const float*)d_in[12];
  const float* tk_b    = (const float*)d_in[13];
  const float* tv_w    = (const float*)d_in[14];
  const float* tv_b    = (const float*)d_in[15];
  const float* to_w    = (const float*)d_in[16];
  const float* to_b    = (const float*)d_in[17];
  const float* fn_g    = (const float*)d_in[18];
  const float* fn_b    = (const float*)d_in[19];
  const float* f1_w    = (const float*)d_in[20];
  const float* f1_b    = (const float*)d_in[21];
  const float* f2_w    = (const float*)d_in[22];
  const float* f2_b    = (const float*)d_in[23];

  char* ws = (char*)d_ws;
  size_t off = 0;
  auto alloc = [&](size_t bytes) -> void* {
    void* p = ws + off;
    off += (bytes + 255) & ~(size_t)255;
    return p;
  };
  unsigned short* Wqkv = (unsigned short*)alloc((size_t)2304*768*2);
  unsigned short* Wo1  = (unsigned short*)alloc((size_t)768*768*2);
  unsigned short* W3   = (unsigned short*)alloc((size_t)2304*768*2);
  float*          b3   = (float*)alloc(2304*4);
  unsigned short* Wto  = (unsigned short*)alloc((size_t)768*768*2);
  unsigned short* Wf1  = (unsigned short*)alloc((size_t)3072*768*2);
  unsigned short* Wf2  = (unsigned short*)alloc((size_t)768*3072*2);
  float*          rope = (float*)alloc(128*32*2*4);
  unsigned short* xn   = (unsigned short*)alloc((size_t)NTOK*768*2);  // shared with attn-out
  unsigned short* qkv  = (unsigned short*)alloc((size_t)NTOK*3072*2); // also FFN h
  unsigned short* xs2  = (unsigned short*)alloc((size_t)NTOK*768*2);
  unsigned short* xt2  = (unsigned short*)alloc((size_t)NTOK*768*2);
  unsigned short* ob   = xn; // alias: xn dead when attn output written

  if (ws_size < off){ sentinel_k<<<1, 64, 0, stream>>>((float*)d_out); return; }

  convert_k<<<1024, 256, 0, stream>>>(sa_in_w, Wqkv, 2304*768/4);
  convert_k<<<512, 256, 0, stream>>>(sa_out_w, Wo1, 768*768/4);
  convert_k<<<512, 256, 0, stream>>>(tq_w, W3, 768*768/4);
  convert_k<<<512, 256, 0, stream>>>(tk_w, W3 + 768*768, 768*768/4);
  convert_k<<<512, 256, 0, stream>>>(tv_w, W3 + 2*768*768, 768*768/4);
  concat3_k<<<3, 256, 0, stream>>>(tq_b, tk_b, tv_b, b3);
  convert_k<<<512, 256, 0, stream>>>(to_w, Wto, 768*768/4);
  convert_k<<<1024, 256, 0, stream>>>(f1_w, Wf1, 3072*768/4);
  convert_k<<<1024, 256, 0, stream>>>(f2_w, Wf2, 768*3072/4);
  rope_k<<<16, 256, 0, stream>>>(rope);

  // spatial block
  ln_k<1><<<NTOK, 256, 0, stream>>>(x, sn_g, sn_b, xn);
  gemm_k<0><<<dim3(256, 18), 256, 0, stream>>>(xn, Wqkv, sa_in_b, nullptr, qkv, 768, 2304);
  sattn_k<<<dim3(2048, 12), 256, 0, stream>>>(qkv, ob);
  gemm_k<2><<<dim3(256, 6), 256, 0, stream>>>(ob, Wo1, sa_out_b, x, xs2, 768, 768);

  // temporal block
  ln_k<0><<<NTOK, 256, 0, stream>>>(xs2, tn_g, tn_b, xn);
  gemm_k<0><<<dim3(256, 18), 256, 0, stream>>>(xn, W3, b3, nullptr, qkv, 768, 2304);
  tattn_k<<<dim3(256, 12), 256, 0, stream>>>(qkv, rope, ob);
  gemm_k<3><<<dim3(256, 6), 256, 0, stream>>>(ob, Wto, to_b, xs2, xt2, 768, 768);

  // FFN
  ln_k<0><<<NTOK, 256, 0, stream>>>(xt2, fn_g, fn_b, xn);
  gemm_k<1><<<dim3(256, 24), 256, 0, stream>>>(xn, Wf1, f1_b, nullptr, qkv, 768, 3072);
  gemm_k<4><<<dim3(256, 6), 256, 0, stream>>>(qkv, Wf2, f2_b, xt2, d_out, 3072, 768);
}

// Round 2
// 1196.496 us; speedup vs baseline: 1.1341x; 1.1341x over previous
//
#include <hip/hip_runtime.h>
#include <stdint.h>

// SpatiotemporalAttention: B=16 W=128 S=16 D=768 H=12 HD=64
//  LN1 -> GEMM qkv -> spatial attn (S=16) -> GEMM +resid(f32) -> xs2
//  LN2 -> GEMM tqkv -> temporal attn (W=128, causal, RoPE) -> GEMM +resid -> xt2
//  LN3 -> GEMM f1+gelu -> GEMM f2 +resid -> d_out (f32)
// GEMMs: 256x256 tile, BK=64, 8-wave, 8-phase-style schedule with counted vmcnt
// (T3+T4), st-swizzled LDS (T2, via pre-swizzled global src + swizzled ds_read),
// setprio around MFMA clusters (T5), packed epilogue stores.

#define NB 16
#define NW 128
#define NS 16
#define ND 768
#define NH 12
#define NTOK 32768

typedef __attribute__((ext_vector_type(8))) short short8;
typedef __attribute__((ext_vector_type(4))) float f32x4;

__device__ __forceinline__ float blo(unsigned v){ return __builtin_bit_cast(float, v << 16); }
__device__ __forceinline__ float bhi(unsigned v){ return __builtin_bit_cast(float, v & 0xffff0000u); }
__device__ __forceinline__ float bus(unsigned short u){ return __builtin_bit_cast(float, ((unsigned)u) << 16); }
__device__ __forceinline__ unsigned short f2b(float f){
  unsigned u = __builtin_bit_cast(unsigned, f);
  u += 0x7fffu + ((u >> 16) & 1u);
  return (unsigned short)(u >> 16);
}
__device__ __forceinline__ void gld_lds16(const void* g, void* l){
  __builtin_amdgcn_global_load_lds((const __attribute__((address_space(1))) void*)g,
                                   (__attribute__((address_space(3))) void*)l, 16, 0, 0);
}

// ---------------- weight convert f32 -> bf16 ----------------
__global__ __launch_bounds__(256) void convert_k(const float* __restrict__ in,
                                                 unsigned short* __restrict__ out, int n4){
  int i = blockIdx.x * 256 + threadIdx.x;
  int stride = gridDim.x * 256;
  for (; i < n4; i += stride){
    float4 v = ((const float4*)in)[i];
    unsigned lo = (unsigned)f2b(v.x) | ((unsigned)f2b(v.y) << 16);
    unsigned hi = (unsigned)f2b(v.z) | ((unsigned)f2b(v.w) << 16);
    ((uint2*)out)[i] = make_uint2(lo, hi);
  }
}

__global__ __launch_bounds__(256) void concat3_k(const float* __restrict__ a, const float* __restrict__ b,
                                                 const float* __restrict__ c, float* __restrict__ o){
  int i = blockIdx.x * 256 + threadIdx.x;
  if (i < 768){ o[i] = a[i]; o[768 + i] = b[i]; o[1536 + i] = c[i]; }
}

__global__ __launch_bounds__(256) void rope_k(float* __restrict__ tab){
  int i = blockIdx.x * 256 + threadIdx.x;
  if (i < 128 * 32){
    int w = i >> 5, p = i & 31;
    float inv = powf(10000.0f, -((float)(2 * p)) / 64.0f);
    float ang = (float)w * inv;
    tab[i * 2] = cosf(ang);
    tab[i * 2 + 1] = sinf(ang);
  }
}

// ---------------- LayerNorm ----------------
template<int INF32>
__global__ __launch_bounds__(256) void ln_k(const void* __restrict__ xin, const float* __restrict__ g,
                                            const float* __restrict__ bt, unsigned short* __restrict__ out){
  const int row = blockIdx.x;
  const int t = threadIdx.x;
  const float* xf = (const float*)xin;
  const unsigned short* xb = (const unsigned short*)xin;
  float v[3];
#pragma unroll
  for (int i = 0; i < 3; ++i){
    int j = t + i * 256;
    v[i] = INF32 ? xf[(size_t)row * 768 + j] : bus(xb[(size_t)row * 768 + j]);
  }
  float s = v[0] + v[1] + v[2];
  float ss = v[0]*v[0] + v[1]*v[1] + v[2]*v[2];
#pragma unroll
  for (int o = 1; o < 64; o <<= 1){ s += __shfl_xor(s, o, 64); ss += __shfl_xor(ss, o, 64); }
  __shared__ float red[8];
  int w = t >> 6;
  if ((t & 63) == 0){ red[w*2] = s; red[w*2+1] = ss; }
  __syncthreads();
  s = red[0] + red[2] + red[4] + red[6];
  ss = red[1] + red[3] + red[5] + red[7];
  float mean = s * (1.0f / 768.0f);
  float var = ss * (1.0f / 768.0f) - mean * mean;
  float rstd = rsqrtf(var + 1e-5f);
#pragma unroll
  for (int i = 0; i < 3; ++i){
    int j = t + i * 256;
    out[(size_t)row * 768 + j] = f2b((v[i] - mean) * rstd * g[j] + bt[j]);
  }
}

// ---------------- GEMM 256x256 / BK=64 / 8 waves / counted-vmcnt schedule ----------------
// out[n][m] = sum_k A[n][k]*Bw[m][k] (+bias, +resid, gelu per MODE)
// MODE 0: bf16 = acc+bias            1: bf16 = gelu(acc+bias)
// MODE 2: bf16 = acc+bias+resid(f32) 3: bf16 = acc+bias+resid(bf16)
// MODE 4: f32  = acc+bias+resid(bf16)
//
// LDS: A ring 4 x 16KB half-slots (half = 128 rows x 64 k), B same. 128 KiB.
// Slot map: X(t,h) -> slot (2t+h)&3. Tile t reads slots {2t,2t+1}&3.
// Stage order (per-thread vmcnt queue): ... B(t+1)x4 [phase1], A(t+2)x4 [phases2,3] ...
// End-of-tile wait vmcnt(4): newest 4 = A(t+2) -> A(t+1),B(t+1) landed. Never 0 mid-loop.
// Race-freedom for A(t+2)->A(t)-slot writes: A(t) ds_reads all drained by phase-0
// lgkmcnt(0), barriers separate. B(t+1) slots disjoint from B(t).
// Swizzle (T2): LDS row r (128B) holds global chunk c at chunk c^(r&7); stage
// pre-swizzles the per-lane GLOBAL address (LDS dest stays linear, m104/m173).
template<int MODE>
__global__ __launch_bounds__(512) void gemm256_k(const unsigned short* __restrict__ A,
                                                 const unsigned short* __restrict__ Bw,
                                                 const float* __restrict__ bias,
                                                 const void* __restrict__ resid,
                                                 void* __restrict__ outp, int K, int M){
  __shared__ char LB[131072];
  char* const Asl = LB;
  char* const Bsl = LB + 65536;
  const int tid = threadIdx.x;
  const int lane = tid & 63, w = tid >> 6;
  const int llo = lane & 15, lhi = lane >> 4;
  const int wm = w >> 2, wn = w & 3;
  const int brow = blockIdx.y << 8, bcol = blockIdx.x << 8;
  const int NT = K >> 6;

  auto stage = [&](const unsigned short* __restrict__ g, int row0, int t, int half, char* slotbase){
    const int r0 = tid >> 3, cp = tid & 7;
#pragma unroll
    for (int j = 0; j < 2; ++j){
      const int r = r0 + (j << 6);
      const unsigned short* src = g + (size_t)(row0 + half * 128 + r) * K + t * 64;
      gld_lds16((const char*)src + ((cp << 4) ^ ((r & 7) << 4)),
                slotbase + (w << 10) + (j << 13));
    }
  };

  // prologue: A(0)h0,h1 ; B(0)h0,h1 ; A(1)h0,h1  -> wait all but A(1)
  stage(A,  brow, 0, 0, Asl);
  stage(A,  brow, 0, 1, Asl + (1 << 14));
  stage(Bw, bcol, 0, 0, Bsl);
  stage(Bw, bcol, 0, 1, Bsl + (1 << 14));
  stage(A,  brow, 1, 0, Asl + (2 << 14));
  stage(A,  brow, 1, 1, Asl + (3 << 14));
  asm volatile("s_waitcnt vmcnt(4)" ::: "memory");
  __builtin_amdgcn_s_barrier();

  f32x4 acc[8][4];
#pragma unroll
  for (int m = 0; m < 8; ++m)
#pragma unroll
    for (int n = 0; n < 4; ++n) acc[m][n] = f32x4{0.f, 0.f, 0.f, 0.f};

  for (int t = 0; t < NT; ++t){
    const char* Ab = Asl + (((2 * t + wm) & 3) << 14);
    const char* Bb = Bsl + (((2 * t + (wn >> 1)) & 3) << 14);

    // phase-0 register loads: all A fragments for this tile
    short8 a[8][2];
#pragma unroll
    for (int m = 0; m < 8; ++m){
      const int rr = (m << 4) + llo;
#pragma unroll
      for (int ks = 0; ks < 2; ++ks)
        a[m][ks] = *(const short8*)(Ab + rr * 128 + (((ks << 6) + (lhi << 4)) ^ ((rr & 7) << 4)));
    }

#pragma unroll
    for (int n = 0; n < 4; ++n){
      const int cc = ((wn & 1) << 6) + (n << 4) + llo;
      short8 b0 = *(const short8*)(Bb + cc * 128 + ((lhi << 4) ^ ((cc & 7) << 4)));
      short8 b1 = *(const short8*)(Bb + cc * 128 + ((64 + (lhi << 4)) ^ ((cc & 7) << 4)));
      if (n == 1 && t + 1 < NT){
        stage(Bw, bcol, t + 1, 0, Bsl + (((2 * t + 2) & 3) << 14));
        stage(Bw, bcol, t + 1, 1, Bsl + (((2 * t + 3) & 3) << 14));
      }
      if (n == 2 && t + 2 < NT)
        stage(A, brow, t + 2, 0, Asl + (((2 * t + 4) & 3) << 14));
      if (n == 3 && t + 2 < NT)
        stage(A, brow, t + 2, 1, Asl + (((2 * t + 5) & 3) << 14));
      __builtin_amdgcn_s_barrier();
      asm volatile("s_waitcnt lgkmcnt(0)" ::: "memory");
      __builtin_amdgcn_s_setprio(1);
#pragma unroll
      for (int m = 0; m < 8; ++m){
        acc[m][n] = __builtin_amdgcn_mfma_f32_16x16x32_bf16(b0, a[m][0], acc[m][n], 0, 0, 0);
        acc[m][n] = __builtin_amdgcn_mfma_f32_16x16x32_bf16(b1, a[m][1], acc[m][n], 0, 0, 0);
      }
      __builtin_amdgcn_s_setprio(0);
      if (n == 3){
        if (t + 2 < NT) asm volatile("s_waitcnt vmcnt(4)" ::: "memory");
        else            asm volatile("s_waitcnt vmcnt(0)" ::: "memory");
      }
      __builtin_amdgcn_s_barrier();
    }
  }

  // epilogue: lane holds 4 consecutive output COLUMNS per fragment (operand-swapped mfma)
  const int orow = brow + (wm << 7);
  const int ocol = bcol + (wn << 6);
  const unsigned short* resb = (const unsigned short*)resid;
  const float* resf = (const float*)resid;
#pragma unroll
  for (int m = 0; m < 8; ++m){
    const int row = orow + (m << 4) + llo;
    const size_t rb = (size_t)row * M;
#pragma unroll
    for (int n = 0; n < 4; ++n){
      const int col = ocol + (n << 4) + (lhi << 2);
      const float4 bv = *(const float4*)&bias[col];
      float v0 = acc[m][n][0] + bv.x;
      float v1 = acc[m][n][1] + bv.y;
      float v2 = acc[m][n][2] + bv.z;
      float v3 = acc[m][n][3] + bv.w;
      const size_t off = rb + col;
      if (MODE == 1){
        v0 = 0.5f * v0 * (1.0f + erff(v0 * 0.70710678118654752f));
        v1 = 0.5f * v1 * (1.0f + erff(v1 * 0.70710678118654752f));
        v2 = 0.5f * v2 * (1.0f + erff(v2 * 0.70710678118654752f));
        v3 = 0.5f * v3 * (1.0f + erff(v3 * 0.70710678118654752f));
      } else if (MODE == 2){
        const float4 rv = *(const float4*)&resf[off];
        v0 += rv.x; v1 += rv.y; v2 += rv.z; v3 += rv.w;
      } else if (MODE == 3 || MODE == 4){
        const uint2 rv = *(const uint2*)&resb[off];
        v0 += blo(rv.x); v1 += bhi(rv.x); v2 += blo(rv.y); v3 += bhi(rv.y);
      }
      if (MODE == 4){
        float4 ov; ov.x = v0; ov.y = v1; ov.z = v2; ov.w = v3;
        *(float4*)&((float*)outp)[off] = ov;
      } else {
        unsigned lo = (unsigned)f2b(v0) | ((unsigned)f2b(v1) << 16);
        unsigned hi = (unsigned)f2b(v2) | ((unsigned)f2b(v3) << 16);
        *(uint2*)&((unsigned short*)outp)[off] = make_uint2(lo, hi);
      }
    }
  }
}

// ---------------- spatial attention: block = (bw, h), S=16, no mask ----------------
__global__ __launch_bounds__(256) void sattn_k(const unsigned short* __restrict__ qkv,
                                               unsigned short* __restrict__ o){
  const int bw = blockIdx.x, h = blockIdx.y;
  const int t = threadIdx.x;
  __shared__ unsigned short qh[16 * 68], kh[16 * 68], vh[16 * 68];
  __shared__ float pl[16 * 17];
  const int row = t >> 4, c4 = t & 15;
  const size_t base = ((size_t)(bw * 16 + row)) * 2304 + h * 64 + c4 * 4;
  *(uint2*)&qh[row * 68 + c4 * 4] = *(const uint2*)&qkv[base];
  *(uint2*)&kh[row * 68 + c4 * 4] = *(const uint2*)&qkv[base + 768];
  *(uint2*)&vh[row * 68 + c4 * 4] = *(const uint2*)&qkv[base + 1536];
  __syncthreads();

  const int q = row, k = c4;
  float s = 0.f;
#pragma unroll
  for (int c = 0; c < 16; ++c){
    uint2 qv = *(const uint2*)&qh[q * 68 + c * 4];
    uint2 kv = *(const uint2*)&kh[k * 68 + c * 4];
    s += blo(qv.x) * blo(kv.x) + bhi(qv.x) * bhi(kv.x);
    s += blo(qv.y) * blo(kv.y) + bhi(qv.y) * bhi(kv.y);
  }
  s *= 0.125f;
  float m = s;
#pragma unroll
  for (int off = 1; off < 16; off <<= 1) m = fmaxf(m, __shfl_xor(m, off, 64));
  float p = __expf(s - m);
  float su = p;
#pragma unroll
  for (int off = 1; off < 16; off <<= 1) su += __shfl_xor(su, off, 64);
  pl[q * 17 + k] = p / su;
  __syncthreads();

  float o0 = 0.f, o1 = 0.f, o2 = 0.f, o3 = 0.f;
#pragma unroll
  for (int kk = 0; kk < 16; ++kk){
    float pw = pl[q * 17 + kk];
    uint2 vv = *(const uint2*)&vh[kk * 68 + c4 * 4];
    o0 += pw * blo(vv.x); o1 += pw * bhi(vv.x);
    o2 += pw * blo(vv.y); o3 += pw * bhi(vv.y);
  }
  const size_t ob = ((size_t)(bw * 16 + q)) * 768 + h * 64 + c4 * 4;
  unsigned r0 = (unsigned)f2b(o0) | ((unsigned)f2b(o1) << 16);
  unsigned r1 = (unsigned)f2b(o2) | ((unsigned)f2b(o3) << 16);
  *(uint2*)&o[ob] = make_uint2(r0, r1);
}

// ---------------- temporal attention: block = (b*16+s, h), W=128, causal, RoPE ----------------
__global__ __launch_bounds__(256) void tattn_k(const unsigned short* __restrict__ qkv,
                                               const float* __restrict__ rope,
                                               unsigned short* __restrict__ o){
  const int bs = blockIdx.x, h = blockIdx.y;
  const int b = bs >> 4, s = bs & 15;
  const int t = threadIdx.x, lane = t & 63, w = t >> 6;
  const int lhi = lane >> 4, llo = lane & 15;
  __shared__ unsigned short Qs[128 * 64];
  __shared__ unsigned short Ks[128 * 64];
  __shared__ unsigned short Vt[64 * 128];
  __shared__ unsigned short P[128 * 128];

  {
    const int r = t >> 1;
    const int dbase = (t & 1) * 32;
    const size_t tokb = ((size_t)((b * 128 + r) * 16 + s)) * 2304 + h * 64;
    const float2* rp = (const float2*)rope;
#pragma unroll
    for (int mch = 0; mch < 4; ++mch){
      const int d0 = dbase + mch * 8;
      uint4 qv = *(const uint4*)&qkv[tokb + d0];
      uint4 kv = *(const uint4*)&qkv[tokb + 768 + d0];
      uint4 vv = *(const uint4*)&qkv[tokb + 1536 + d0];
      unsigned qin[4] = {qv.x, qv.y, qv.z, qv.w};
      unsigned kin[4] = {kv.x, kv.y, kv.z, kv.w};
      unsigned qo[4], ko[4];
#pragma unroll
      for (int j = 0; j < 4; ++j){
        float2 cssn = rp[r * 32 + (d0 >> 1) + j];
        float cs = cssn.x, sn = cssn.y;
        float qe = blo(qin[j]), qd = bhi(qin[j]);
        float ke = blo(kin[j]), kd = bhi(kin[j]);
        qo[j] = (unsigned)f2b(qe * cs - qd * sn) | ((unsigned)f2b(qe * sn + qd * cs) << 16);
        ko[j] = (unsigned)f2b(ke * cs - kd * sn) | ((unsigned)f2b(ke * sn + kd * cs) << 16);
      }
      const int byq = r * 128 + ((d0 * 2) ^ ((r & 7) << 4));
      *(uint4*)((char*)Qs + byq) = make_uint4(qo[0], qo[1], qo[2], qo[3]);
      *(uint4*)((char*)Ks + byq) = make_uint4(ko[0], ko[1], ko[2], ko[3]);
      unsigned vin[4] = {vv.x, vv.y, vv.z, vv.w};
#pragma unroll
      for (int j = 0; j < 8; ++j){
        const int d = d0 + j;
        unsigned short val = (j & 1) ? (unsigned short)(vin[j >> 1] >> 16)
                                     : (unsigned short)(vin[j >> 1] & 0xffffu);
        *(unsigned short*)((char*)Vt + d * 256 + ((r * 2) ^ ((d & 7) << 4))) = val;
      }
    }
  }
  __syncthreads();

  const int qbase = w * 32;
  f32x4 st[8][2];
#pragma unroll
  for (int i = 0; i < 8; ++i){ st[i][0] = f32x4{0.f,0.f,0.f,0.f}; st[i][1] = f32x4{0.f,0.f,0.f,0.f}; }
#pragma unroll
  for (int kd = 0; kd < 2; ++kd){
    short8 bq[2];
#pragma unroll
    for (int fq = 0; fq < 2; ++fq){
      const int qr = qbase + fq * 16 + llo;
      bq[fq] = *(const short8*)((const char*)Qs + qr * 128 + ((kd * 64 + lhi * 16) ^ ((qr & 7) << 4)));
    }
#pragma unroll
    for (int fk = 0; fk < 8; ++fk){
      const int kr = fk * 16 + llo;
      short8 ak = *(const short8*)((const char*)Ks + kr * 128 + ((kd * 64 + lhi * 16) ^ ((kr & 7) << 4)));
      st[fk][0] = __builtin_amdgcn_mfma_f32_16x16x32_bf16(ak, bq[0], st[fk][0], 0, 0, 0);
      st[fk][1] = __builtin_amdgcn_mfma_f32_16x16x32_bf16(ak, bq[1], st[fk][1], 0, 0, 0);
    }
  }

#pragma unroll
  for (int fq = 0; fq < 2; ++fq){
    const int qg = qbase + fq * 16 + llo;
    float m = -1e30f;
#pragma unroll
    for (int fk = 0; fk < 8; ++fk)
#pragma unroll
      for (int rr = 0; rr < 4; ++rr){
        const int kg = fk * 16 + lhi * 4 + rr;
        float sv = (kg <= qg) ? st[fk][fq][rr] : -1e30f;
        st[fk][fq][rr] = sv;
        m = fmaxf(m, sv);
      }
    m = fmaxf(m, __shfl_xor(m, 16, 64));
    m = fmaxf(m, __shfl_xor(m, 32, 64));
    float su = 0.f;
#pragma unroll
    for (int fk = 0; fk < 8; ++fk)
#pragma unroll
      for (int rr = 0; rr < 4; ++rr){
        float p = __expf((st[fk][fq][rr] - m) * 0.125f);
        st[fk][fq][rr] = p;
        su += p;
      }
    su += __shfl_xor(su, 16, 64);
    su += __shfl_xor(su, 32, 64);
    const float rs = 1.0f / su;
#pragma unroll
    for (int fk = 0; fk < 8; ++fk){
      const int kk = fk * 16 + lhi * 4;
      unsigned lo = (unsigned)f2b(st[fk][fq][0] * rs) | ((unsigned)f2b(st[fk][fq][1] * rs) << 16);
      unsigned hi = (unsigned)f2b(st[fk][fq][2] * rs) | ((unsigned)f2b(st[fk][fq][3] * rs) << 16);
      *(uint2*)((char*)P + qg * 256 + ((kk * 2) ^ ((qg & 7) << 4))) = make_uint2(lo, hi);
    }
  }
  __syncthreads();

  f32x4 oacc[2][4];
#pragma unroll
  for (int i = 0; i < 2; ++i)
#pragma unroll
    for (int j = 0; j < 4; ++j) oacc[i][j] = f32x4{0.f,0.f,0.f,0.f};
#pragma unroll
  for (int ks = 0; ks < 4; ++ks){
    short8 pa[2];
#pragma unroll
    for (int fq = 0; fq < 2; ++fq){
      const int qr = qbase + fq * 16 + llo;
      pa[fq] = *(const short8*)((const char*)P + qr * 256 + ((ks * 64 + lhi * 16) ^ ((qr & 7) << 4)));
    }
#pragma unroll
    for (int fd = 0; fd < 4; ++fd){
      const int dr = fd * 16 + llo;
      short8 vb = *(const short8*)((const char*)Vt + dr * 256 + ((ks * 64 + lhi * 16) ^ ((dr & 7) << 4)));
      oacc[0][fd] = __builtin_amdgcn_mfma_f32_16x16x32_bf16(pa[0], vb, oacc[0][fd], 0, 0, 0);
      oacc[1][fd] = __builtin_amdgcn_mfma_f32_16x16x32_bf16(pa[1], vb, oacc[1][fd], 0, 0, 0);
    }
  }

#pragma unroll
  for (int fq = 0; fq < 2; ++fq)
#pragma unroll
    for (int fd = 0; fd < 4; ++fd)
#pragma unroll
      for (int rr = 0; rr < 4; ++rr){
        const int qg = qbase + fq * 16 + lhi * 4 + rr;
        const int d = fd * 16 + llo;
        const size_t ob = ((size_t)((b * 128 + qg) * 16 + s)) * 768 + h * 64 + d;
        o[ob] = f2b(oacc[fq][fd][rr]);
      }
}

__global__ __launch_bounds__(256) void sentinel_k(float* out){
  if (blockIdx.x == 0 && threadIdx.x == 0) out[0] = 12345.0f;
}

// ---------------- launch ----------------
extern "C" void kernel_launch(void* const* d_in, const int* in_sizes, int n_in,
                              void* d_out, int out_size, void* d_ws, size_t ws_size,
                              hipStream_t stream){
  const float* x       = (const float*)d_in[0];
  const float* sn_g    = (const float*)d_in[2];
  const float* sn_b    = (const float*)d_in[3];
  const float* sa_in_w = (const float*)d_in[4];
  const float* sa_in_b = (const float*)d_in[5];
  const float* sa_out_w= (const float*)d_in[6];
  const float* sa_out_b= (const float*)d_in[7];
  const float* tn_g    = (const float*)d_in[8];
  const float* tn_b    = (const float*)d_in[9];
  const float* tq_w    = (const float*)d_in[10];
  const float* tq_b    = (const float*)d_in[11];
  const float* tk_w    = (const float*)d_in[12];
  const float* tk_b    = (const float*)d_in[13];
  const float* tv_w    = (const float*)d_in[14];
  const float* tv_b    = (const float*)d_in[15];
  const float* to_w    = (const float*)d_in[16];
  const float* to_b    = (const float*)d_in[17];
  const float* fn_g    = (const float*)d_in[18];
  const float* fn_b    = (const float*)d_in[19];
  const float* f1_w    = (const float*)d_in[20];
  const float* f1_b    = (const float*)d_in[21];
  const float* f2_w    = (const float*)d_in[22];
  const float* f2_b    = (const float*)d_in[23];

  char* ws = (char*)d_ws;
  size_t off = 0;
  auto alloc = [&](size_t bytes) -> void* {
    void* p = ws + off;
    off += (bytes + 255) & ~(size_t)255;
    return p;
  };
  unsigned short* Wqkv = (unsigned short*)alloc((size_t)2304*768*2);
  unsigned short* Wo1  = (unsigned short*)alloc((size_t)768*768*2);
  unsigned short* W3   = (unsigned short*)alloc((size_t)2304*768*2);
  float*          b3   = (float*)alloc(2304*4);
  unsigned short* Wto  = (unsigned short*)alloc((size_t)768*768*2);
  unsigned short* Wf1  = (unsigned short*)alloc((size_t)3072*768*2);
  unsigned short* Wf2  = (unsigned short*)alloc((size_t)768*3072*2);
  float*          rope = (float*)alloc(128*32*2*4);
  unsigned short* xn   = (unsigned short*)alloc((size_t)NTOK*768*2);
  unsigned short* qkv  = (unsigned short*)alloc((size_t)NTOK*3072*2);
  unsigned short* xs2  = (unsigned short*)alloc((size_t)NTOK*768*2);
  unsigned short* xt2  = (unsigned short*)alloc((size_t)NTOK*768*2);
  unsigned short* ob   = xn; // alias: xn dead when attn output written

  if (ws_size < off){ sentinel_k<<<1, 64, 0, stream>>>((float*)d_out); return; }

  convert_k<<<1024, 256, 0, stream>>>(sa_in_w, Wqkv, 2304*768/4);
  convert_k<<<512, 256, 0, stream>>>(sa_out_w, Wo1, 768*768/4);
  convert_k<<<512, 256, 0, stream>>>(tq_w, W3, 768*768/4);
  convert_k<<<512, 256, 0, stream>>>(tk_w, W3 + 768*768, 768*768/4);
  convert_k<<<512, 256, 0, stream>>>(tv_w, W3 + 2*768*768, 768*768/4);
  concat3_k<<<3, 256, 0, stream>>>(tq_b, tk_b, tv_b, b3);
  convert_k<<<512, 256, 0, stream>>>(to_w, Wto, 768*768/4);
  convert_k<<<1024, 256, 0, stream>>>(f1_w, Wf1, 3072*768/4);
  convert_k<<<1024, 256, 0, stream>>>(f2_w, Wf2, 768*3072/4);
  rope_k<<<16, 256, 0, stream>>>(rope);

  // spatial block
  ln_k<1><<<NTOK, 256, 0, stream>>>(x, sn_g, sn_b, xn);
  gemm256_k<0><<<dim3(9, 128), 512, 0, stream>>>(xn, Wqkv, sa_in_b, nullptr, qkv, 768, 2304);
  sattn_k<<<dim3(2048, 12), 256, 0, stream>>>(qkv, ob);
  gemm256_k<2><<<dim3(3, 128), 512, 0, stream>>>(ob, Wo1, sa_out_b, x, xs2, 768, 768);

  // temporal block
  ln_k<0><<<NTOK, 256, 0, stream>>>(xs2, tn_g, tn_b, xn);
  gemm256_k<0><<<dim3(9, 128), 512, 0, stream>>>(xn, W3, b3, nullptr, qkv, 768, 2304);
  tattn_k<<<dim3(256, 12), 256, 0, stream>>>(qkv, rope, ob);
  gemm256_k<3><<<dim3(3, 128), 512, 0, stream>>>(ob, Wto, to_b, xs2, xt2, 768, 768);

  // FFN
  ln_k<0><<<NTOK, 256, 0, stream>>>(xt2, fn_g, fn_b, xn);
  gemm256_k<1><<<dim3(12, 128), 512, 0, stream>>>(xn, Wf1, f1_b, nullptr, qkv, 768, 3072);
  gemm256_k<4><<<dim3(3, 128), 512, 0, stream>>>(qkv, Wf2, f2_b, xt2, d_out, 3072, 768);
}

// Round 3
// 1140.849 us; speedup vs baseline: 1.1895x; 1.0488x over previous
//
#include <hip/hip_runtime.h>
#include <stdint.h>

// SpatiotemporalAttention: B=16 W=128 S=16 D=768 H=12 HD=64
//  LN1 -> GEMM qkv -> spatial attn (S=16) -> GEMM +resid(f32) -> xs2
//  LN2 -> GEMM tqkv -> temporal attn (W=128, causal, RoPE) -> GEMM +resid -> xt2
//  LN3 -> GEMM f1+gelu -> GEMM f2 +resid -> d_out (f32)
// GEMMs: 256x256 tile, BK=64, 8 waves, m201-style 4-phase K-loop: each phase
// {own ds_read subtile + 1 half-tile stage + barrier + lgkm(0) + 16 MFMA + barrier},
// counted vmcnt(4) once per tile (T3+T4), T2 swizzle (pre-swizzled global src),
// T5 setprio around MFMA clusters, packed epilogue stores.

#define NB 16
#define NW 128
#define NS 16
#define ND 768
#define NH 12
#define NTOK 32768

typedef __attribute__((ext_vector_type(8))) short short8;
typedef __attribute__((ext_vector_type(4))) float f32x4;

__device__ __forceinline__ float blo(unsigned v){ return __builtin_bit_cast(float, v << 16); }
__device__ __forceinline__ float bhi(unsigned v){ return __builtin_bit_cast(float, v & 0xffff0000u); }
__device__ __forceinline__ float bus(unsigned short u){ return __builtin_bit_cast(float, ((unsigned)u) << 16); }
__device__ __forceinline__ unsigned short f2b(float f){
  unsigned u = __builtin_bit_cast(unsigned, f);
  u += 0x7fffu + ((u >> 16) & 1u);
  return (unsigned short)(u >> 16);
}
__device__ __forceinline__ void gld_lds16(const void* g, void* l){
  __builtin_amdgcn_global_load_lds((const __attribute__((address_space(1))) void*)g,
                                   (__attribute__((address_space(3))) void*)l, 16, 0, 0);
}

// ---------------- weight convert f32 -> bf16 ----------------
__global__ __launch_bounds__(256) void convert_k(const float* __restrict__ in,
                                                 unsigned short* __restrict__ out, int n4){
  int i = blockIdx.x * 256 + threadIdx.x;
  int stride = gridDim.x * 256;
  for (; i < n4; i += stride){
    float4 v = ((const float4*)in)[i];
    unsigned lo = (unsigned)f2b(v.x) | ((unsigned)f2b(v.y) << 16);
    unsigned hi = (unsigned)f2b(v.z) | ((unsigned)f2b(v.w) << 16);
    ((uint2*)out)[i] = make_uint2(lo, hi);
  }
}

__global__ __launch_bounds__(256) void concat3_k(const float* __restrict__ a, const float* __restrict__ b,
                                                 const float* __restrict__ c, float* __restrict__ o){
  int i = blockIdx.x * 256 + threadIdx.x;
  if (i < 768){ o[i] = a[i]; o[768 + i] = b[i]; o[1536 + i] = c[i]; }
}

__global__ __launch_bounds__(256) void rope_k(float* __restrict__ tab){
  int i = blockIdx.x * 256 + threadIdx.x;
  if (i < 128 * 32){
    int w = i >> 5, p = i & 31;
    float inv = powf(10000.0f, -((float)(2 * p)) / 64.0f);
    float ang = (float)w * inv;
    tab[i * 2] = cosf(ang);
    tab[i * 2 + 1] = sinf(ang);
  }
}

// ---------------- LayerNorm ----------------
template<int INF32>
__global__ __launch_bounds__(256) void ln_k(const void* __restrict__ xin, const float* __restrict__ g,
                                            const float* __restrict__ bt, unsigned short* __restrict__ out){
  const int row = blockIdx.x;
  const int t = threadIdx.x;
  const float* xf = (const float*)xin;
  const unsigned short* xb = (const unsigned short*)xin;
  float v[3];
#pragma unroll
  for (int i = 0; i < 3; ++i){
    int j = t + i * 256;
    v[i] = INF32 ? xf[(size_t)row * 768 + j] : bus(xb[(size_t)row * 768 + j]);
  }
  float s = v[0] + v[1] + v[2];
  float ss = v[0]*v[0] + v[1]*v[1] + v[2]*v[2];
#pragma unroll
  for (int o = 1; o < 64; o <<= 1){ s += __shfl_xor(s, o, 64); ss += __shfl_xor(ss, o, 64); }
  __shared__ float red[8];
  int w = t >> 6;
  if ((t & 63) == 0){ red[w*2] = s; red[w*2+1] = ss; }
  __syncthreads();
  s = red[0] + red[2] + red[4] + red[6];
  ss = red[1] + red[3] + red[5] + red[7];
  float mean = s * (1.0f / 768.0f);
  float var = ss * (1.0f / 768.0f) - mean * mean;
  float rstd = rsqrtf(var + 1e-5f);
#pragma unroll
  for (int i = 0; i < 3; ++i){
    int j = t + i * 256;
    out[(size_t)row * 768 + j] = f2b((v[i] - mean) * rstd * g[j] + bt[j]);
  }
}

// ---------------- GEMM 256x256 / BK=64 / 8 waves / 4-phase m201-style ----------------
// out[n][m] = sum_k A[n][k]*Bw[m][k] (+bias, +resid, gelu per MODE)
// MODE 0: bf16 = acc+bias            1: bf16 = gelu(acc+bias)
// MODE 2: bf16 = acc+bias+resid(f32) 3: bf16 = acc+bias+resid(bf16)
// MODE 4: f32  = acc+bias+resid(bf16)
//
// LDS: A/B each a ring of 4 half-slots (half = 128 rows x 64 k = 16 KB). 128 KiB.
// Slot map: X(t,h) -> (2t+h)&3. Tile t reads slots {2t,2t+1}&3.
// Phases per tile: p0 {rd A-mh0(8)+B-nh0(4); stage B(t+1)h0; mfma mh0*nh0}
//                  p1 {rd A-mh1(8);          stage B(t+1)h1; mfma mh1*nh0}
//                  p2 {rd B-nh1(4);          stage A(t+2)h0; mfma mh0*nh1}
//                  p3 {                      stage A(t+2)h1; mfma mh1*nh1; vmcnt(4)}
// Race-freedom: A(t) reads all drained by p1's lgkm(0) BEFORE p1's trailing
// barrier, so A(t+2) stages (p2/p3, into A(t)'s slots) are ordered after them
// for every wave. B(t+1) slots disjoint from B(t). vmcnt(4) at tile end leaves
// exactly A(t+2)x4 in flight -> A(t+1),B(t+1) landed; never drains to 0 mid-loop.
// Swizzle (T2): LDS[r][c] holds global chunk c^(r&7); stage pre-swizzles the
// per-lane GLOBAL address (LDS dest stays linear, m104/m173); reads XOR the same.
template<int MODE>
__global__ __launch_bounds__(512) void gemm256_k(const unsigned short* __restrict__ A,
                                                 const unsigned short* __restrict__ Bw,
                                                 const float* __restrict__ bias,
                                                 const void* __restrict__ resid,
                                                 void* __restrict__ outp, int K, int M){
  __shared__ char LB[131072];
  char* const Asl = LB;
  char* const Bsl = LB + 65536;
  const int tid = threadIdx.x;
  const int lane = tid & 63, w = tid >> 6;
  const int llo = lane & 15, lhi = lane >> 4;
  const int wm = w >> 2, wn = w & 3;
  const int brow = blockIdx.y << 8, bcol = blockIdx.x << 8;
  const int NT = K >> 6;

  // staging: thread -> row r0=tid>>3 (+64 per j), 16B chunk cp=tid&7; swizzle on global side
  const int r0 = tid >> 3, cp = tid & 7;
  const int swz = (cp << 4) ^ ((r0 & 7) << 4);
  const char* aG = (const char*)(A + (size_t)(brow + r0) * K) + swz;
  const char* bG = (const char*)(Bw + (size_t)(bcol + r0) * K) + swz;
  const int J  = K * 128;   // 64-row step (bytes)
  const int Hh = K * 256;   // 128-row (half) step (bytes)
  const int ldst = w << 10; // wave-uniform LDS base within slot (HW adds lane*16)

  auto stage = [&](const char* g, int gb, char* slotbase){
    gld_lds16(g + gb,     slotbase + ldst);
    gld_lds16(g + gb + J, slotbase + ldst + (1 << 13));
  };

  // prologue: A(0)h0,h1 ; B(0)h0,h1 ; A(1)h0,h1 ; wait all but A(1)
  stage(aG, 0,        Asl);
  stage(aG, Hh,       Asl + (1 << 14));
  stage(bG, 0,        Bsl);
  stage(bG, Hh,       Bsl + (1 << 14));
  stage(aG, 128,      Asl + (2 << 14));
  stage(aG, 128 + Hh, Asl + (3 << 14));
  asm volatile("s_waitcnt vmcnt(4)" ::: "memory");
  __builtin_amdgcn_s_barrier();

  f32x4 acc[8][4];
#pragma unroll
  for (int m = 0; m < 8; ++m)
#pragma unroll
    for (int n = 0; n < 4; ++n) acc[m][n] = f32x4{0.f, 0.f, 0.f, 0.f};

  for (int t = 0; t < NT; ++t){
    const char* Ab = Asl + (((2 * t + wm) & 3) << 14);
    const char* Bb = Bsl + (((2 * t + (wn >> 1)) & 3) << 14);
    const int tb = t << 7;
    short8 a0[4][2], a1[4][2], b0[2][2], b1[2][2];

    // ---- p0: A-mh0 + B-nh0 reads; stage B(t+1)h0; mfma quadrant (mh0,nh0)
#pragma unroll
    for (int mi = 0; mi < 4; ++mi){
      const int rr = (mi << 4) + llo;
#pragma unroll
      for (int ks = 0; ks < 2; ++ks)
        a0[mi][ks] = *(const short8*)(Ab + rr * 128 + (((ks << 6) + (lhi << 4)) ^ ((rr & 7) << 4)));
    }
#pragma unroll
    for (int ni = 0; ni < 2; ++ni){
      const int cc = ((wn & 1) << 6) + (ni << 4) + llo;
#pragma unroll
      for (int ks = 0; ks < 2; ++ks)
        b0[ni][ks] = *(const short8*)(Bb + cc * 128 + (((ks << 6) + (lhi << 4)) ^ ((cc & 7) << 4)));
    }
    if (t + 1 < NT) stage(bG, tb + 128, Bsl + (((2 * t + 2) & 3) << 14));
    __builtin_amdgcn_s_barrier();
    asm volatile("s_waitcnt lgkmcnt(0)" ::: "memory");
    __builtin_amdgcn_s_setprio(1);
#pragma unroll
    for (int mi = 0; mi < 4; ++mi)
#pragma unroll
      for (int ni = 0; ni < 2; ++ni){
        acc[mi][ni] = __builtin_amdgcn_mfma_f32_16x16x32_bf16(b0[ni][0], a0[mi][0], acc[mi][ni], 0, 0, 0);
        acc[mi][ni] = __builtin_amdgcn_mfma_f32_16x16x32_bf16(b0[ni][1], a0[mi][1], acc[mi][ni], 0, 0, 0);
      }
    __builtin_amdgcn_s_setprio(0);
    __builtin_amdgcn_s_barrier();

    // ---- p1: A-mh1 reads; stage B(t+1)h1; mfma (mh1,nh0)
#pragma unroll
    for (int mi = 0; mi < 4; ++mi){
      const int rr = 64 + (mi << 4) + llo;
#pragma unroll
      for (int ks = 0; ks < 2; ++ks)
        a1[mi][ks] = *(const short8*)(Ab + rr * 128 + (((ks << 6) + (lhi << 4)) ^ ((rr & 7) << 4)));
    }
    if (t + 1 < NT) stage(bG, tb + 128 + Hh, Bsl + (((2 * t + 3) & 3) << 14));
    __builtin_amdgcn_s_barrier();
    asm volatile("s_waitcnt lgkmcnt(0)" ::: "memory");
    __builtin_amdgcn_s_setprio(1);
#pragma unroll
    for (int mi = 0; mi < 4; ++mi)
#pragma unroll
      for (int ni = 0; ni < 2; ++ni){
        acc[4 + mi][ni] = __builtin_amdgcn_mfma_f32_16x16x32_bf16(b0[ni][0], a1[mi][0], acc[4 + mi][ni], 0, 0, 0);
        acc[4 + mi][ni] = __builtin_amdgcn_mfma_f32_16x16x32_bf16(b0[ni][1], a1[mi][1], acc[4 + mi][ni], 0, 0, 0);
      }
    __builtin_amdgcn_s_setprio(0);
    __builtin_amdgcn_s_barrier();

    // ---- p2: B-nh1 reads; stage A(t+2)h0; mfma (mh0,nh1)
#pragma unroll
    for (int ni = 0; ni < 2; ++ni){
      const int cc = ((wn & 1) << 6) + 32 + (ni << 4) + llo;
#pragma unroll
      for (int ks = 0; ks < 2; ++ks)
        b1[ni][ks] = *(const short8*)(Bb + cc * 128 + (((ks << 6) + (lhi << 4)) ^ ((cc & 7) << 4)));
    }
    if (t + 2 < NT) stage(aG, tb + 256, Asl + (((2 * t + 4) & 3) << 14));
    __builtin_amdgcn_s_barrier();
    asm volatile("s_waitcnt lgkmcnt(0)" ::: "memory");
    __builtin_amdgcn_s_setprio(1);
#pragma unroll
    for (int mi = 0; mi < 4; ++mi)
#pragma unroll
      for (int ni = 0; ni < 2; ++ni){
        acc[mi][2 + ni] = __builtin_amdgcn_mfma_f32_16x16x32_bf16(b1[ni][0], a0[mi][0], acc[mi][2 + ni], 0, 0, 0);
        acc[mi][2 + ni] = __builtin_amdgcn_mfma_f32_16x16x32_bf16(b1[ni][1], a0[mi][1], acc[mi][2 + ni], 0, 0, 0);
      }
    __builtin_amdgcn_s_setprio(0);
    __builtin_amdgcn_s_barrier();

    // ---- p3: stage A(t+2)h1; mfma (mh1,nh1); counted vmcnt
    if (t + 2 < NT) stage(aG, tb + 256 + Hh, Asl + (((2 * t + 5) & 3) << 14));
    __builtin_amdgcn_s_barrier();
    asm volatile("s_waitcnt lgkmcnt(0)" ::: "memory");
    __builtin_amdgcn_s_setprio(1);
#pragma unroll
    for (int mi = 0; mi < 4; ++mi)
#pragma unroll
      for (int ni = 0; ni < 2; ++ni){
        acc[4 + mi][2 + ni] = __builtin_amdgcn_mfma_f32_16x16x32_bf16(b1[ni][0], a1[mi][0], acc[4 + mi][2 + ni], 0, 0, 0);
        acc[4 + mi][2 + ni] = __builtin_amdgcn_mfma_f32_16x16x32_bf16(b1[ni][1], a1[mi][1], acc[4 + mi][2 + ni], 0, 0, 0);
      }
    __builtin_amdgcn_s_setprio(0);
    if (t + 2 < NT) asm volatile("s_waitcnt vmcnt(4)" ::: "memory");
    else            asm volatile("s_waitcnt vmcnt(0)" ::: "memory");
    __builtin_amdgcn_s_barrier();
  }

  // epilogue: lane holds 4 consecutive output COLUMNS per fragment
  const int orow = brow + (wm << 7);
  const int ocol = bcol + (wn << 6);
  const unsigned short* resb = (const unsigned short*)resid;
  const float* resf = (const float*)resid;
#pragma unroll
  for (int m = 0; m < 8; ++m){
    const int row = orow + (m << 4) + llo;
    const size_t rb = (size_t)row * M;
#pragma unroll
    for (int n = 0; n < 4; ++n){
      const int col = ocol + (n << 4) + (lhi << 2);
      const float4 bv = *(const float4*)&bias[col];
      float v0 = acc[m][n][0] + bv.x;
      float v1 = acc[m][n][1] + bv.y;
      float v2 = acc[m][n][2] + bv.z;
      float v3 = acc[m][n][3] + bv.w;
      const size_t off = rb + col;
      if (MODE == 1){
        // tanh-form GELU: v*sigmoid(1.5957691216 v + 0.0713548163 v^3)
        float y0 = v0 * (1.5957691216f + 0.0713548163f * v0 * v0);
        float y1 = v1 * (1.5957691216f + 0.0713548163f * v1 * v1);
        float y2 = v2 * (1.5957691216f + 0.0713548163f * v2 * v2);
        float y3 = v3 * (1.5957691216f + 0.0713548163f * v3 * v3);
        v0 = v0 / (1.0f + __expf(-y0));
        v1 = v1 / (1.0f + __expf(-y1));
        v2 = v2 / (1.0f + __expf(-y2));
        v3 = v3 / (1.0f + __expf(-y3));
      } else if (MODE == 2){
        const float4 rv = *(const float4*)&resf[off];
        v0 += rv.x; v1 += rv.y; v2 += rv.z; v3 += rv.w;
      } else if (MODE == 3 || MODE == 4){
        const uint2 rv = *(const uint2*)&resb[off];
        v0 += blo(rv.x); v1 += bhi(rv.x); v2 += blo(rv.y); v3 += bhi(rv.y);
      }
      if (MODE == 4){
        float4 ov; ov.x = v0; ov.y = v1; ov.z = v2; ov.w = v3;
        *(float4*)&((float*)outp)[off] = ov;
      } else {
        unsigned lo = (unsigned)f2b(v0) | ((unsigned)f2b(v1) << 16);
        unsigned hi = (unsigned)f2b(v2) | ((unsigned)f2b(v3) << 16);
        *(uint2*)&((unsigned short*)outp)[off] = make_uint2(lo, hi);
      }
    }
  }
}

// ---------------- spatial attention: block = (bw, h), S=16, no mask ----------------
__global__ __launch_bounds__(256) void sattn_k(const unsigned short* __restrict__ qkv,
                                               unsigned short* __restrict__ o){
  const int bw = blockIdx.x, h = blockIdx.y;
  const int t = threadIdx.x;
  __shared__ unsigned short qh[16 * 68], kh[16 * 68], vh[16 * 68];
  __shared__ float pl[16 * 17];
  const int row = t >> 4, c4 = t & 15;
  const size_t base = ((size_t)(bw * 16 + row)) * 2304 + h * 64 + c4 * 4;
  *(uint2*)&qh[row * 68 + c4 * 4] = *(const uint2*)&qkv[base];
  *(uint2*)&kh[row * 68 + c4 * 4] = *(const uint2*)&qkv[base + 768];
  *(uint2*)&vh[row * 68 + c4 * 4] = *(const uint2*)&qkv[base + 1536];
  __syncthreads();

  const int q = row, k = c4;
  float s = 0.f;
#pragma unroll
  for (int c = 0; c < 16; ++c){
    uint2 qv = *(const uint2*)&qh[q * 68 + c * 4];
    uint2 kv = *(const uint2*)&kh[k * 68 + c * 4];
    s += blo(qv.x) * blo(kv.x) + bhi(qv.x) * bhi(kv.x);
    s += blo(qv.y) * blo(kv.y) + bhi(qv.y) * bhi(kv.y);
  }
  s *= 0.125f;
  float m = s;
#pragma unroll
  for (int off = 1; off < 16; off <<= 1) m = fmaxf(m, __shfl_xor(m, off, 64));
  float p = __expf(s - m);
  float su = p;
#pragma unroll
  for (int off = 1; off < 16; off <<= 1) su += __shfl_xor(su, off, 64);
  pl[q * 17 + k] = p / su;
  __syncthreads();

  float o0 = 0.f, o1 = 0.f, o2 = 0.f, o3 = 0.f;
#pragma unroll
  for (int kk = 0; kk < 16; ++kk){
    float pw = pl[q * 17 + kk];
    uint2 vv = *(const uint2*)&vh[kk * 68 + c4 * 4];
    o0 += pw * blo(vv.x); o1 += pw * bhi(vv.x);
    o2 += pw * blo(vv.y); o3 += pw * bhi(vv.y);
  }
  const size_t ob = ((size_t)(bw * 16 + q)) * 768 + h * 64 + c4 * 4;
  unsigned r0 = (unsigned)f2b(o0) | ((unsigned)f2b(o1) << 16);
  unsigned r1 = (unsigned)f2b(o2) | ((unsigned)f2b(o3) << 16);
  *(uint2*)&o[ob] = make_uint2(r0, r1);
}

// ---------------- temporal attention: block = (b*16+s, h), W=128, causal, RoPE ----------------
__global__ __launch_bounds__(256) void tattn_k(const unsigned short* __restrict__ qkv,
                                               const float* __restrict__ rope,
                                               unsigned short* __restrict__ o){
  const int bs = blockIdx.x, h = blockIdx.y;
  const int b = bs >> 4, s = bs & 15;
  const int t = threadIdx.x, lane = t & 63, w = t >> 6;
  const int lhi = lane >> 4, llo = lane & 15;
  __shared__ unsigned short Qs[128 * 64];
  __shared__ unsigned short Ks[128 * 64];
  __shared__ unsigned short Vt[64 * 128];
  __shared__ unsigned short P[128 * 128];

  {
    const int r = t >> 1;
    const int dbase = (t & 1) * 32;
    const size_t tokb = ((size_t)((b * 128 + r) * 16 + s)) * 2304 + h * 64;
    const float2* rp = (const float2*)rope;
#pragma unroll
    for (int mch = 0; mch < 4; ++mch){
      const int d0 = dbase + mch * 8;
      uint4 qv = *(const uint4*)&qkv[tokb + d0];
      uint4 kv = *(const uint4*)&qkv[tokb + 768 + d0];
      uint4 vv = *(const uint4*)&qkv[tokb + 1536 + d0];
      unsigned qin[4] = {qv.x, qv.y, qv.z, qv.w};
      unsigned kin[4] = {kv.x, kv.y, kv.z, kv.w};
      unsigned qo[4], ko[4];
#pragma unroll
      for (int j = 0; j < 4; ++j){
        float2 cssn = rp[r * 32 + (d0 >> 1) + j];
        float cs = cssn.x, sn = cssn.y;
        float qe = blo(qin[j]), qd = bhi(qin[j]);
        float ke = blo(kin[j]), kd = bhi(kin[j]);
        qo[j] = (unsigned)f2b(qe * cs - qd * sn) | ((unsigned)f2b(qe * sn + qd * cs) << 16);
        ko[j] = (unsigned)f2b(ke * cs - kd * sn) | ((unsigned)f2b(ke * sn + kd * cs) << 16);
      }
      const int byq = r * 128 + ((d0 * 2) ^ ((r & 7) << 4));
      *(uint4*)((char*)Qs + byq) = make_uint4(qo[0], qo[1], qo[2], qo[3]);
      *(uint4*)((char*)Ks + byq) = make_uint4(ko[0], ko[1], ko[2], ko[3]);
      unsigned vin[4] = {vv.x, vv.y, vv.z, vv.w};
#pragma unroll
      for (int j = 0; j < 8; ++j){
        const int d = d0 + j;
        unsigned short val = (j & 1) ? (unsigned short)(vin[j >> 1] >> 16)
                                     : (unsigned short)(vin[j >> 1] & 0xffffu);
        *(unsigned short*)((char*)Vt + d * 256 + ((r * 2) ^ ((d & 7) << 4))) = val;
      }
    }
  }
  __syncthreads();

  const int qbase = w * 32;
  f32x4 st[8][2];
#pragma unroll
  for (int i = 0; i < 8; ++i){ st[i][0] = f32x4{0.f,0.f,0.f,0.f}; st[i][1] = f32x4{0.f,0.f,0.f,0.f}; }
#pragma unroll
  for (int kd = 0; kd < 2; ++kd){
    short8 bq[2];
#pragma unroll
    for (int fq = 0; fq < 2; ++fq){
      const int qr = qbase + fq * 16 + llo;
      bq[fq] = *(const short8*)((const char*)Qs + qr * 128 + ((kd * 64 + lhi * 16) ^ ((qr & 7) << 4)));
    }
#pragma unroll
    for (int fk = 0; fk < 8; ++fk){
      const int kr = fk * 16 + llo;
      short8 ak = *(const short8*)((const char*)Ks + kr * 128 + ((kd * 64 + lhi * 16) ^ ((kr & 7) << 4)));
      st[fk][0] = __builtin_amdgcn_mfma_f32_16x16x32_bf16(ak, bq[0], st[fk][0], 0, 0, 0);
      st[fk][1] = __builtin_amdgcn_mfma_f32_16x16x32_bf16(ak, bq[1], st[fk][1], 0, 0, 0);
    }
  }

#pragma unroll
  for (int fq = 0; fq < 2; ++fq){
    const int qg = qbase + fq * 16 + llo;
    float m = -1e30f;
#pragma unroll
    for (int fk = 0; fk < 8; ++fk)
#pragma unroll
      for (int rr = 0; rr < 4; ++rr){
        const int kg = fk * 16 + lhi * 4 + rr;
        float sv = (kg <= qg) ? st[fk][fq][rr] : -1e30f;
        st[fk][fq][rr] = sv;
        m = fmaxf(m, sv);
      }
    m = fmaxf(m, __shfl_xor(m, 16, 64));
    m = fmaxf(m, __shfl_xor(m, 32, 64));
    float su = 0.f;
#pragma unroll
    for (int fk = 0; fk < 8; ++fk)
#pragma unroll
      for (int rr = 0; rr < 4; ++rr){
        float p = __expf((st[fk][fq][rr] - m) * 0.125f);
        st[fk][fq][rr] = p;
        su += p;
      }
    su += __shfl_xor(su, 16, 64);
    su += __shfl_xor(su, 32, 64);
    const float rs = 1.0f / su;
#pragma unroll
    for (int fk = 0; fk < 8; ++fk){
      const int kk = fk * 16 + lhi * 4;
      unsigned lo = (unsigned)f2b(st[fk][fq][0] * rs) | ((unsigned)f2b(st[fk][fq][1] * rs) << 16);
      unsigned hi = (unsigned)f2b(st[fk][fq][2] * rs) | ((unsigned)f2b(st[fk][fq][3] * rs) << 16);
      *(uint2*)((char*)P + qg * 256 + ((kk * 2) ^ ((qg & 7) << 4))) = make_uint2(lo, hi);
    }
  }
  __syncthreads();

  f32x4 oacc[2][4];
#pragma unroll
  for (int i = 0; i < 2; ++i)
#pragma unroll
    for (int j = 0; j < 4; ++j) oacc[i][j] = f32x4{0.f,0.f,0.f,0.f};
#pragma unroll
  for (int ks = 0; ks < 4; ++ks){
    short8 pa[2];
#pragma unroll
    for (int fq = 0; fq < 2; ++fq){
      const int qr = qbase + fq * 16 + llo;
      pa[fq] = *(const short8*)((const char*)P + qr * 256 + ((ks * 64 + lhi * 16) ^ ((qr & 7) << 4)));
    }
#pragma unroll
    for (int fd = 0; fd < 4; ++fd){
      const int dr = fd * 16 + llo;
      short8 vb = *(const short8*)((const char*)Vt + dr * 256 + ((ks * 64 + lhi * 16) ^ ((dr & 7) << 4)));
      oacc[0][fd] = __builtin_amdgcn_mfma_f32_16x16x32_bf16(pa[0], vb, oacc[0][fd], 0, 0, 0);
      oacc[1][fd] = __builtin_amdgcn_mfma_f32_16x16x32_bf16(pa[1], vb, oacc[1][fd], 0, 0, 0);
    }
  }

#pragma unroll
  for (int fq = 0; fq < 2; ++fq)
#pragma unroll
    for (int fd = 0; fd < 4; ++fd)
#pragma unroll
      for (int rr = 0; rr < 4; ++rr){
        const int qg = qbase + fq * 16 + lhi * 4 + rr;
        const int d = fd * 16 + llo;
        const size_t ob = ((size_t)((b * 128 + qg) * 16 + s)) * 768 + h * 64 + d;
        o[ob] = f2b(oacc[fq][fd][rr]);
      }
}

__global__ __launch_bounds__(256) void sentinel_k(float* out){
  if (blockIdx.x == 0 && threadIdx.x == 0) out[0] = 12345.0f;
}

// ---------------- launch ----------------
extern "C" void kernel_launch(void* const* d_in, const int* in_sizes, int n_in,
                              void* d_out, int out_size, void* d_ws, size_t ws_size,
                              hipStream_t stream){
  const float* x       = (const float*)d_in[0];
  const float* sn_g    = (const float*)d_in[2];
  const float* sn_b    = (const float*)d_in[3];
  const float* sa_in_w = (const float*)d_in[4];
  const float* sa_in_b = (const float*)d_in[5];
  const float* sa_out_w= (const float*)d_in[6];
  const float* sa_out_b= (const float*)d_in[7];
  const float* tn_g    = (const float*)d_in[8];
  const float* tn_b    = (const float*)d_in[9];
  const float* tq_w    = (const float*)d_in[10];
  const float* tq_b    = (const float*)d_in[11];
  const float* tk_w    = (const float*)d_in[12];
  const float* tk_b    = (const float*)d_in[13];
  const float* tv_w    = (const float*)d_in[14];
  const float* tv_b    = (const float*)d_in[15];
  const float* to_w    = (const float*)d_in[16];
  const float* to_b    = (const float*)d_in[17];
  const float* fn_g    = (const float*)d_in[18];
  const float* fn_b    = (const float*)d_in[19];
  const float* f1_w    = (const float*)d_in[20];
  const float* f1_b    = (const float*)d_in[21];
  const float* f2_w    = (const float*)d_in[22];
  const float* f2_b    = (const float*)d_in[23];

  char* ws = (char*)d_ws;
  size_t off = 0;
  auto alloc = [&](size_t bytes) -> void* {
    void* p = ws + off;
    off += (bytes + 255) & ~(size_t)255;
    return p;
  };
  unsigned short* Wqkv = (unsigned short*)alloc((size_t)2304*768*2);
  unsigned short* Wo1  = (unsigned short*)alloc((size_t)768*768*2);
  unsigned short* W3   = (unsigned short*)alloc((size_t)2304*768*2);
  float*          b3   = (float*)alloc(2304*4);
  unsigned short* Wto  = (unsigned short*)alloc((size_t)768*768*2);
  unsigned short* Wf1  = (unsigned short*)alloc((size_t)3072*768*2);
  unsigned short* Wf2  = (unsigned short*)alloc((size_t)768*3072*2);
  float*          rope = (float*)alloc(128*32*2*4);
  unsigned short* xn   = (unsigned short*)alloc((size_t)NTOK*768*2);
  unsigned short* qkv  = (unsigned short*)alloc((size_t)NTOK*3072*2);
  unsigned short* xs2  = (unsigned short*)alloc((size_t)NTOK*768*2);
  unsigned short* xt2  = (unsigned short*)alloc((size_t)NTOK*768*2);
  unsigned short* ob   = xn; // alias: xn dead when attn output written

  if (ws_size < off){ sentinel_k<<<1, 64, 0, stream>>>((float*)d_out); return; }

  convert_k<<<1024, 256, 0, stream>>>(sa_in_w, Wqkv, 2304*768/4);
  convert_k<<<512, 256, 0, stream>>>(sa_out_w, Wo1, 768*768/4);
  convert_k<<<512, 256, 0, stream>>>(tq_w, W3, 768*768/4);
  convert_k<<<512, 256, 0, stream>>>(tk_w, W3 + 768*768, 768*768/4);
  convert_k<<<512, 256, 0, stream>>>(tv_w, W3 + 2*768*768, 768*768/4);
  concat3_k<<<3, 256, 0, stream>>>(tq_b, tk_b, tv_b, b3);
  convert_k<<<512, 256, 0, stream>>>(to_w, Wto, 768*768/4);
  convert_k<<<1024, 256, 0, stream>>>(f1_w, Wf1, 3072*768/4);
  convert_k<<<1024, 256, 0, stream>>>(f2_w, Wf2, 768*3072/4);
  rope_k<<<16, 256, 0, stream>>>(rope);

  // spatial block
  ln_k<1><<<NTOK, 256, 0, stream>>>(x, sn_g, sn_b, xn);
  gemm256_k<0><<<dim3(9, 128), 512, 0, stream>>>(xn, Wqkv, sa_in_b, nullptr, qkv, 768, 2304);
  sattn_k<<<dim3(2048, 12), 256, 0, stream>>>(qkv, ob);
  gemm256_k<2><<<dim3(3, 128), 512, 0, stream>>>(ob, Wo1, sa_out_b, x, xs2, 768, 768);

  // temporal block
  ln_k<0><<<NTOK, 256, 0, stream>>>(xs2, tn_g, tn_b, xn);
  gemm256_k<0><<<dim3(9, 128), 512, 0, stream>>>(xn, W3, b3, nullptr, qkv, 768, 2304);
  tattn_k<<<dim3(256, 12), 256, 0, stream>>>(qkv, rope, ob);
  gemm256_k<3><<<dim3(3, 128), 512, 0, stream>>>(ob, Wto, to_b, xs2, xt2, 768, 768);

  // FFN
  ln_k<0><<<NTOK, 256, 0, stream>>>(xt2, fn_g, fn_b, xn);
  gemm256_k<1><<<dim3(12, 128), 512, 0, stream>>>(xn, Wf1, f1_b, nullptr, qkv, 768, 3072);
  gemm256_k<4><<<dim3(3, 128), 512, 0, stream>>>(qkv, Wf2, f2_b, xt2, d_out, 3072, 768);
}

// Round 4
// 1122.005 us; speedup vs baseline: 1.2094x; 1.0168x over previous
//
#include <hip/hip_runtime.h>
#include <stdint.h>

// SpatiotemporalAttention: B=16 W=128 S=16 D=768 H=12 HD=64
//  LN1 -> GEMM qkv -> spatial attn (S=16) -> GEMM +resid(f32) -> xs2
//  LN2 -> GEMM tqkv -> temporal attn (W=128, causal, RoPE) -> GEMM +resid -> xt2
//  LN3 -> GEMM f1+gelu -> GEMM f2 +resid -> d_out (f32)
// GEMMs: BMx256 tile (BM=256 or 128 via MROWS), BK=64, 8 waves, m201-style
// 4-phase K-loop, counted vmcnt (T3+T4), T2 swizzle via pre-swizzled global src,
// T5 setprio, T1 XCD-aware block swizzle (y-band per XCD), packed stores.

#define NB 16
#define NW 128
#define NS 16
#define ND 768
#define NH 12
#define NTOK 32768

typedef __attribute__((ext_vector_type(8))) short short8;
typedef __attribute__((ext_vector_type(4))) float f32x4;

__device__ __forceinline__ float blo(unsigned v){ return __builtin_bit_cast(float, v << 16); }
__device__ __forceinline__ float bhi(unsigned v){ return __builtin_bit_cast(float, v & 0xffff0000u); }
__device__ __forceinline__ float bus(unsigned short u){ return __builtin_bit_cast(float, ((unsigned)u) << 16); }
__device__ __forceinline__ unsigned short f2b(float f){
  unsigned u = __builtin_bit_cast(unsigned, f);
  u += 0x7fffu + ((u >> 16) & 1u);
  return (unsigned short)(u >> 16);
}
__device__ __forceinline__ void gld_lds16(const void* g, void* l){
  __builtin_amdgcn_global_load_lds((const __attribute__((address_space(1))) void*)g,
                                   (__attribute__((address_space(3))) void*)l, 16, 0, 0);
}

// ---------------- weight convert f32 -> bf16 ----------------
__global__ __launch_bounds__(256) void convert_k(const float* __restrict__ in,
                                                 unsigned short* __restrict__ out, int n4){
  int i = blockIdx.x * 256 + threadIdx.x;
  int stride = gridDim.x * 256;
  for (; i < n4; i += stride){
    float4 v = ((const float4*)in)[i];
    unsigned lo = (unsigned)f2b(v.x) | ((unsigned)f2b(v.y) << 16);
    unsigned hi = (unsigned)f2b(v.z) | ((unsigned)f2b(v.w) << 16);
    ((uint2*)out)[i] = make_uint2(lo, hi);
  }
}

__global__ __launch_bounds__(256) void concat3_k(const float* __restrict__ a, const float* __restrict__ b,
                                                 const float* __restrict__ c, float* __restrict__ o){
  int i = blockIdx.x * 256 + threadIdx.x;
  if (i < 768){ o[i] = a[i]; o[768 + i] = b[i]; o[1536 + i] = c[i]; }
}

__global__ __launch_bounds__(256) void rope_k(float* __restrict__ tab){
  int i = blockIdx.x * 256 + threadIdx.x;
  if (i < 128 * 32){
    int w = i >> 5, p = i & 31;
    float inv = powf(10000.0f, -((float)(2 * p)) / 64.0f);
    float ang = (float)w * inv;
    tab[i * 2] = cosf(ang);
    tab[i * 2 + 1] = sinf(ang);
  }
}

// ---------------- LayerNorm ----------------
template<int INF32>
__global__ __launch_bounds__(256) void ln_k(const void* __restrict__ xin, const float* __restrict__ g,
                                            const float* __restrict__ bt, unsigned short* __restrict__ out){
  const int row = blockIdx.x;
  const int t = threadIdx.x;
  const float* xf = (const float*)xin;
  const unsigned short* xb = (const unsigned short*)xin;
  float v[3];
#pragma unroll
  for (int i = 0; i < 3; ++i){
    int j = t + i * 256;
    v[i] = INF32 ? xf[(size_t)row * 768 + j] : bus(xb[(size_t)row * 768 + j]);
  }
  float s = v[0] + v[1] + v[2];
  float ss = v[0]*v[0] + v[1]*v[1] + v[2]*v[2];
#pragma unroll
  for (int o = 1; o < 64; o <<= 1){ s += __shfl_xor(s, o, 64); ss += __shfl_xor(ss, o, 64); }
  __shared__ float red[8];
  int w = t >> 6;
  if ((t & 63) == 0){ red[w*2] = s; red[w*2+1] = ss; }
  __syncthreads();
  s = red[0] + red[2] + red[4] + red[6];
  ss = red[1] + red[3] + red[5] + red[7];
  float mean = s * (1.0f / 768.0f);
  float var = ss * (1.0f / 768.0f) - mean * mean;
  float rstd = rsqrtf(var + 1e-5f);
#pragma unroll
  for (int i = 0; i < 3; ++i){
    int j = t + i * 256;
    out[(size_t)row * 768 + j] = f2b((v[i] - mean) * rstd * g[j] + bt[j]);
  }
}

// ---------------- GEMM BMx256 / BK=64 / 8 waves / 4-phase m201-style ----------------
// out[n][m] = sum_k A[n][k]*Bw[m][k] (+bias, +resid, gelu per MODE)
// MODE 0: bf16 = acc+bias            1: bf16 = gelu(acc+bias)
// MODE 2: bf16 = acc+bias+resid(f32) 3: bf16 = acc+bias+resid(bf16)
// MODE 4: f32  = acc+bias+resid(bf16)
// MROWS: per-wave m-fragments. 8 -> BM=256 (LDS 128K), 4 -> BM=128 (LDS 96K).
//
// LDS: A/B each a ring of 4 half-slots (A half = BM/2 rows x 64 k; B half = 128x64).
// Slot map: X(t,h) -> (2t+h)&3. Tile t reads slots {2t,2t+1}&3.
// Phases: p0 {rd A-mh0+B-nh0; stage B(t+1)h0; mfma q00}
//         p1 {rd A-mh1;       stage B(t+1)h1; mfma q10}
//         p2 {rd B-nh1;       stage A(t+2)h0; mfma q01}
//         p3 {                stage A(t+2)h1; mfma q11; vmcnt(2*NJA)}
// Race-freedom: all A(t) reads drained by p1's lgkm(0) before p1's trailing
// barrier -> A(t+2) stages (p2/p3) ordered after them for every wave. B(t+1)
// slots disjoint from B(t). vmcnt leaves exactly A(t+2) in flight mid-loop.
// T2 swizzle: LDS[r] holds global 16B-chunk c at c^(r&7); pre-swizzled global
// src (LDS dest linear, m104/m173); ds_reads XOR the same.
// T1: bijective XCD swizzle (nwg%8==0 for all launches): each XCD owns a
// contiguous y-band -> A panels fetched by exactly one XCD's L2.
template<int MODE, int MROWS>
__global__ __launch_bounds__(512) void gemm256_k(const unsigned short* __restrict__ A,
                                                 const unsigned short* __restrict__ Bw,
                                                 const float* __restrict__ bias,
                                                 const void* __restrict__ resid,
                                                 void* __restrict__ outp, int K, int M){
  constexpr int MH = MROWS / 2;
  constexpr int ASH = (MROWS == 8) ? 14 : 13;     // A half-slot byte shift
  constexpr int NJA = MROWS / 4;                  // gld_lds per A-half stage
  constexpr int LDSZ = 4 * (1 << ASH) + 65536;
  __shared__ char LB[LDSZ];
  char* const Asl = LB;
  char* const Bsl = LB + 4 * (1 << ASH);
  const int tid = threadIdx.x;
  const int lane = tid & 63, w = tid >> 6;
  const int llo = lane & 15, lhi = lane >> 4;
  const int wm = w >> 2, wn = w & 3;
  const int NT = K >> 6;

  // T1 swizzle: contiguous y-band per XCD
  const int gx = gridDim.x;
  const int nwg = gx * gridDim.y;
  const int orig = blockIdx.y * gx + blockIdx.x;
  const int lin = (nwg & 7) ? orig : ((orig & 7) * (nwg >> 3) + (orig >> 3));
  const int by = lin / gx, bx = lin - by * gx;
  const int brow = by * (MROWS << 5);
  const int bcol = bx << 8;

  // staging: thread -> row r0=tid>>3 (+64 per j), 16B chunk cp=tid&7; swizzle on global side
  const int r0 = tid >> 3, cp = tid & 7;
  const int swz = (cp << 4) ^ ((r0 & 7) << 4);
  const char* aG = (const char*)(A + (size_t)(brow + r0) * K) + swz;
  const char* bG = (const char*)(Bw + (size_t)(bcol + r0) * K) + swz;
  const int J  = K * 128;             // 64-row step (bytes)
  const int Ha = K * (MROWS << 5);    // A half step (MROWS*16 rows, bytes)
  const int Hb = K * 256;             // B half step (128 rows, bytes)
  const int ldst = w << 10;           // wave-uniform LDS base (HW adds lane*16)

  auto stage_a = [&](int gb, char* slotbase){
    gld_lds16(aG + gb, slotbase + ldst);
    if constexpr (NJA == 2) gld_lds16(aG + gb + J, slotbase + ldst + (1 << 13));
  };
  auto stage_b = [&](int gb, char* slotbase){
    gld_lds16(bG + gb, slotbase + ldst);
    gld_lds16(bG + gb + J, slotbase + ldst + (1 << 13));
  };

  // prologue: A(0)h0,h1 ; B(0)h0,h1 ; A(1)h0,h1 ; wait all but A(1)
  stage_a(0,        Asl);
  stage_a(Ha,       Asl + (1 << ASH));
  stage_b(0,        Bsl);
  stage_b(Hb,       Bsl + (1 << 14));
  stage_a(128,      Asl + (2 << ASH));
  stage_a(128 + Ha, Asl + (3 << ASH));
  if constexpr (NJA == 2) asm volatile("s_waitcnt vmcnt(4)" ::: "memory");
  else                    asm volatile("s_waitcnt vmcnt(2)" ::: "memory");
  __builtin_amdgcn_s_barrier();

  f32x4 acc[MROWS][4];
#pragma unroll
  for (int m = 0; m < MROWS; ++m)
#pragma unroll
    for (int n = 0; n < 4; ++n) acc[m][n] = f32x4{0.f, 0.f, 0.f, 0.f};

  for (int t = 0; t < NT; ++t){
    const char* Ab = Asl + (((2 * t + wm) & 3) << ASH);
    const char* Bb = Bsl + (((2 * t + (wn >> 1)) & 3) << 14);
    const int tb = t << 7;
    short8 a0[MH][2], a1[MH][2], b0[2][2], b1[2][2];

    // ---- p0: A-mh0 + B-nh0 reads; stage B(t+1)h0; mfma quadrant (mh0,nh0)
#pragma unroll
    for (int mi = 0; mi < MH; ++mi){
      const int rr = (mi << 4) + llo;
#pragma unroll
      for (int ks = 0; ks < 2; ++ks)
        a0[mi][ks] = *(const short8*)(Ab + rr * 128 + (((ks << 6) + (lhi << 4)) ^ ((rr & 7) << 4)));
    }
#pragma unroll
    for (int ni = 0; ni < 2; ++ni){
      const int cc = ((wn & 1) << 6) + (ni << 4) + llo;
#pragma unroll
      for (int ks = 0; ks < 2; ++ks)
        b0[ni][ks] = *(const short8*)(Bb + cc * 128 + (((ks << 6) + (lhi << 4)) ^ ((cc & 7) << 4)));
    }
    if (t + 1 < NT) stage_b(tb + 128, Bsl + (((2 * t + 2) & 3) << 14));
    __builtin_amdgcn_s_barrier();
    asm volatile("s_waitcnt lgkmcnt(0)" ::: "memory");
    __builtin_amdgcn_s_setprio(1);
#pragma unroll
    for (int mi = 0; mi < MH; ++mi)
#pragma unroll
      for (int ni = 0; ni < 2; ++ni){
        acc[mi][ni] = __builtin_amdgcn_mfma_f32_16x16x32_bf16(b0[ni][0], a0[mi][0], acc[mi][ni], 0, 0, 0);
        acc[mi][ni] = __builtin_amdgcn_mfma_f32_16x16x32_bf16(b0[ni][1], a0[mi][1], acc[mi][ni], 0, 0, 0);
      }
    __builtin_amdgcn_s_setprio(0);
    __builtin_amdgcn_s_barrier();

    // ---- p1: A-mh1 reads; stage B(t+1)h1; mfma (mh1,nh0)
#pragma unroll
    for (int mi = 0; mi < MH; ++mi){
      const int rr = (MH << 4) + (mi << 4) + llo;
#pragma unroll
      for (int ks = 0; ks < 2; ++ks)
        a1[mi][ks] = *(const short8*)(Ab + rr * 128 + (((ks << 6) + (lhi << 4)) ^ ((rr & 7) << 4)));
    }
    if (t + 1 < NT) stage_b(tb + 128 + Hb, Bsl + (((2 * t + 3) & 3) << 14));
    __builtin_amdgcn_s_barrier();
    asm volatile("s_waitcnt lgkmcnt(0)" ::: "memory");
    __builtin_amdgcn_s_setprio(1);
#pragma unroll
    for (int mi = 0; mi < MH; ++mi)
#pragma unroll
      for (int ni = 0; ni < 2; ++ni){
        acc[MH + mi][ni] = __builtin_amdgcn_mfma_f32_16x16x32_bf16(b0[ni][0], a1[mi][0], acc[MH + mi][ni], 0, 0, 0);
        acc[MH + mi][ni] = __builtin_amdgcn_mfma_f32_16x16x32_bf16(b0[ni][1], a1[mi][1], acc[MH + mi][ni], 0, 0, 0);
      }
    __builtin_amdgcn_s_setprio(0);
    __builtin_amdgcn_s_barrier();

    // ---- p2: B-nh1 reads; stage A(t+2)h0; mfma (mh0,nh1)
#pragma unroll
    for (int ni = 0; ni < 2; ++ni){
      const int cc = ((wn & 1) << 6) + 32 + (ni << 4) + llo;
#pragma unroll
      for (int ks = 0; ks < 2; ++ks)
        b1[ni][ks] = *(const short8*)(Bb + cc * 128 + (((ks << 6) + (lhi << 4)) ^ ((cc & 7) << 4)));
    }
    if (t + 2 < NT) stage_a(tb + 256, Asl + (((2 * t + 4) & 3) << ASH));
    __builtin_amdgcn_s_barrier();
    asm volatile("s_waitcnt lgkmcnt(0)" ::: "memory");
    __builtin_amdgcn_s_setprio(1);
#pragma unroll
    for (int mi = 0; mi < MH; ++mi)
#pragma unroll
      for (int ni = 0; ni < 2; ++ni){
        acc[mi][2 + ni] = __builtin_amdgcn_mfma_f32_16x16x32_bf16(b1[ni][0], a0[mi][0], acc[mi][2 + ni], 0, 0, 0);
        acc[mi][2 + ni] = __builtin_amdgcn_mfma_f32_16x16x32_bf16(b1[ni][1], a0[mi][1], acc[mi][2 + ni], 0, 0, 0);
      }
    __builtin_amdgcn_s_setprio(0);
    __builtin_amdgcn_s_barrier();

    // ---- p3: stage A(t+2)h1; mfma (mh1,nh1); counted vmcnt
    if (t + 2 < NT) stage_a(tb + 256 + Ha, Asl + (((2 * t + 5) & 3) << ASH));
    __builtin_amdgcn_s_barrier();
    asm volatile("s_waitcnt lgkmcnt(0)" ::: "memory");
    __builtin_amdgcn_s_setprio(1);
#pragma unroll
    for (int mi = 0; mi < MH; ++mi)
#pragma unroll
      for (int ni = 0; ni < 2; ++ni){
        acc[MH + mi][2 + ni] = __builtin_amdgcn_mfma_f32_16x16x32_bf16(b1[ni][0], a1[mi][0], acc[MH + mi][2 + ni], 0, 0, 0);
        acc[MH + mi][2 + ni] = __builtin_amdgcn_mfma_f32_16x16x32_bf16(b1[ni][1], a1[mi][1], acc[MH + mi][2 + ni], 0, 0, 0);
      }
    __builtin_amdgcn_s_setprio(0);
    if (t + 2 < NT){
      if constexpr (NJA == 2) asm volatile("s_waitcnt vmcnt(4)" ::: "memory");
      else                    asm volatile("s_waitcnt vmcnt(2)" ::: "memory");
    } else {
      asm volatile("s_waitcnt vmcnt(0)" ::: "memory");
    }
    __builtin_amdgcn_s_barrier();
  }

  // epilogue: lane holds 4 consecutive output COLUMNS per fragment
  const int orow = brow + wm * (MROWS << 4);
  const int ocol = bcol + (wn << 6);
  const unsigned short* resb = (const unsigned short*)resid;
  const float* resf = (const float*)resid;
#pragma unroll
  for (int m = 0; m < MROWS; ++m){
    const int row = orow + (m << 4) + llo;
    const size_t rb = (size_t)row * M;
#pragma unroll
    for (int n = 0; n < 4; ++n){
      const int col = ocol + (n << 4) + (lhi << 2);
      const float4 bv = *(const float4*)&bias[col];
      float v0 = acc[m][n][0] + bv.x;
      float v1 = acc[m][n][1] + bv.y;
      float v2 = acc[m][n][2] + bv.z;
      float v3 = acc[m][n][3] + bv.w;
      const size_t off = rb + col;
      if (MODE == 1){
        float y0 = v0 * (1.5957691216f + 0.0713548163f * v0 * v0);
        float y1 = v1 * (1.5957691216f + 0.0713548163f * v1 * v1);
        float y2 = v2 * (1.5957691216f + 0.0713548163f * v2 * v2);
        float y3 = v3 * (1.5957691216f + 0.0713548163f * v3 * v3);
        v0 = v0 / (1.0f + __expf(-y0));
        v1 = v1 / (1.0f + __expf(-y1));
        v2 = v2 / (1.0f + __expf(-y2));
        v3 = v3 / (1.0f + __expf(-y3));
      } else if (MODE == 2){
        const float4 rv = *(const float4*)&resf[off];
        v0 += rv.x; v1 += rv.y; v2 += rv.z; v3 += rv.w;
      } else if (MODE == 3 || MODE == 4){
        const uint2 rv = *(const uint2*)&resb[off];
        v0 += blo(rv.x); v1 += bhi(rv.x); v2 += blo(rv.y); v3 += bhi(rv.y);
      }
      if (MODE == 4){
        float4 ov; ov.x = v0; ov.y = v1; ov.z = v2; ov.w = v3;
        *(float4*)&((float*)outp)[off] = ov;
      } else {
        unsigned lo = (unsigned)f2b(v0) | ((unsigned)f2b(v1) << 16);
        unsigned hi = (unsigned)f2b(v2) | ((unsigned)f2b(v3) << 16);
        *(uint2*)&((unsigned short*)outp)[off] = make_uint2(lo, hi);
      }
    }
  }
}

// ---------------- spatial attention: block = (bw, h), S=16, no mask ----------------
__global__ __launch_bounds__(256) void sattn_k(const unsigned short* __restrict__ qkv,
                                               unsigned short* __restrict__ o){
  const int bw = blockIdx.x, h = blockIdx.y;
  const int t = threadIdx.x;
  __shared__ unsigned short qh[16 * 68], kh[16 * 68], vh[16 * 68];
  __shared__ float pl[16 * 17];
  const int row = t >> 4, c4 = t & 15;
  const size_t base = ((size_t)(bw * 16 + row)) * 2304 + h * 64 + c4 * 4;
  *(uint2*)&qh[row * 68 + c4 * 4] = *(const uint2*)&qkv[base];
  *(uint2*)&kh[row * 68 + c4 * 4] = *(const uint2*)&qkv[base + 768];
  *(uint2*)&vh[row * 68 + c4 * 4] = *(const uint2*)&qkv[base + 1536];
  __syncthreads();

  const int q = row, k = c4;
  float s = 0.f;
#pragma unroll
  for (int c = 0; c < 16; ++c){
    uint2 qv = *(const uint2*)&qh[q * 68 + c * 4];
    uint2 kv = *(const uint2*)&kh[k * 68 + c * 4];
    s += blo(qv.x) * blo(kv.x) + bhi(qv.x) * bhi(kv.x);
    s += blo(qv.y) * blo(kv.y) + bhi(qv.y) * bhi(kv.y);
  }
  s *= 0.125f;
  float m = s;
#pragma unroll
  for (int off = 1; off < 16; off <<= 1) m = fmaxf(m, __shfl_xor(m, off, 64));
  float p = __expf(s - m);
  float su = p;
#pragma unroll
  for (int off = 1; off < 16; off <<= 1) su += __shfl_xor(su, off, 64);
  pl[q * 17 + k] = p / su;
  __syncthreads();

  float o0 = 0.f, o1 = 0.f, o2 = 0.f, o3 = 0.f;
#pragma unroll
  for (int kk = 0; kk < 16; ++kk){
    float pw = pl[q * 17 + kk];
    uint2 vv = *(const uint2*)&vh[kk * 68 + c4 * 4];
    o0 += pw * blo(vv.x); o1 += pw * bhi(vv.x);
    o2 += pw * blo(vv.y); o3 += pw * bhi(vv.y);
  }
  const size_t ob = ((size_t)(bw * 16 + q)) * 768 + h * 64 + c4 * 4;
  unsigned r0 = (unsigned)f2b(o0) | ((unsigned)f2b(o1) << 16);
  unsigned r1 = (unsigned)f2b(o2) | ((unsigned)f2b(o3) << 16);
  *(uint2*)&o[ob] = make_uint2(r0, r1);
}

// ---------------- temporal attention: block = (b*16+s, h), W=128, causal, RoPE ----------------
__global__ __launch_bounds__(256) void tattn_k(const unsigned short* __restrict__ qkv,
                                               const float* __restrict__ rope,
                                               unsigned short* __restrict__ o){
  const int bs = blockIdx.x, h = blockIdx.y;
  const int b = bs >> 4, s = bs & 15;
  const int t = threadIdx.x, lane = t & 63, w = t >> 6;
  const int lhi = lane >> 4, llo = lane & 15;
  __shared__ unsigned short Qs[128 * 64];
  __shared__ unsigned short Ks[128 * 64];
  __shared__ unsigned short Vt[64 * 128];
  __shared__ unsigned short P[128 * 128];

  {
    const int r = t >> 1;
    const int dbase = (t & 1) * 32;
    const size_t tokb = ((size_t)((b * 128 + r) * 16 + s)) * 2304 + h * 64;
    const float2* rp = (const float2*)rope;
#pragma unroll
    for (int mch = 0; mch < 4; ++mch){
      const int d0 = dbase + mch * 8;
      uint4 qv = *(const uint4*)&qkv[tokb + d0];
      uint4 kv = *(const uint4*)&qkv[tokb + 768 + d0];
      uint4 vv = *(const uint4*)&qkv[tokb + 1536 + d0];
      unsigned qin[4] = {qv.x, qv.y, qv.z, qv.w};
      unsigned kin[4] = {kv.x, kv.y, kv.z, kv.w};
      unsigned qo[4], ko[4];
#pragma unroll
      for (int j = 0; j < 4; ++j){
        float2 cssn = rp[r * 32 + (d0 >> 1) + j];
        float cs = cssn.x, sn = cssn.y;
        float qe = blo(qin[j]), qd = bhi(qin[j]);
        float ke = blo(kin[j]), kd = bhi(kin[j]);
        qo[j] = (unsigned)f2b(qe * cs - qd * sn) | ((unsigned)f2b(qe * sn + qd * cs) << 16);
        ko[j] = (unsigned)f2b(ke * cs - kd * sn) | ((unsigned)f2b(ke * sn + kd * cs) << 16);
      }
      const int byq = r * 128 + ((d0 * 2) ^ ((r & 7) << 4));
      *(uint4*)((char*)Qs + byq) = make_uint4(qo[0], qo[1], qo[2], qo[3]);
      *(uint4*)((char*)Ks + byq) = make_uint4(ko[0], ko[1], ko[2], ko[3]);
      unsigned vin[4] = {vv.x, vv.y, vv.z, vv.w};
#pragma unroll
      for (int j = 0; j < 8; ++j){
        const int d = d0 + j;
        unsigned short val = (j & 1) ? (unsigned short)(vin[j >> 1] >> 16)
                                     : (unsigned short)(vin[j >> 1] & 0xffffu);
        *(unsigned short*)((char*)Vt + d * 256 + ((r * 2) ^ ((d & 7) << 4))) = val;
      }
    }
  }
  __syncthreads();

  const int qbase = w * 32;
  f32x4 st[8][2];
#pragma unroll
  for (int i = 0; i < 8; ++i){ st[i][0] = f32x4{0.f,0.f,0.f,0.f}; st[i][1] = f32x4{0.f,0.f,0.f,0.f}; }
#pragma unroll
  for (int kd = 0; kd < 2; ++kd){
    short8 bq[2];
#pragma unroll
    for (int fq = 0; fq < 2; ++fq){
      const int qr = qbase + fq * 16 + llo;
      bq[fq] = *(const short8*)((const char*)Qs + qr * 128 + ((kd * 64 + lhi * 16) ^ ((qr & 7) << 4)));
    }
#pragma unroll
    for (int fk = 0; fk < 8; ++fk){
      const int kr = fk * 16 + llo;
      short8 ak = *(const short8*)((const char*)Ks + kr * 128 + ((kd * 64 + lhi * 16) ^ ((kr & 7) << 4)));
      st[fk][0] = __builtin_amdgcn_mfma_f32_16x16x32_bf16(ak, bq[0], st[fk][0], 0, 0, 0);
      st[fk][1] = __builtin_amdgcn_mfma_f32_16x16x32_bf16(ak, bq[1], st[fk][1], 0, 0, 0);
    }
  }

#pragma unroll
  for (int fq = 0; fq < 2; ++fq){
    const int qg = qbase + fq * 16 + llo;
    float m = -1e30f;
#pragma unroll
    for (int fk = 0; fk < 8; ++fk)
#pragma unroll
      for (int rr = 0; rr < 4; ++rr){
        const int kg = fk * 16 + lhi * 4 + rr;
        float sv = (kg <= qg) ? st[fk][fq][rr] : -1e30f;
        st[fk][fq][rr] = sv;
        m = fmaxf(m, sv);
      }
    m = fmaxf(m, __shfl_xor(m, 16, 64));
    m = fmaxf(m, __shfl_xor(m, 32, 64));
    float su = 0.f;
#pragma unroll
    for (int fk = 0; fk < 8; ++fk)
#pragma unroll
      for (int rr = 0; rr < 4; ++rr){
        float p = __expf((st[fk][fq][rr] - m) * 0.125f);
        st[fk][fq][rr] = p;
        su += p;
      }
    su += __shfl_xor(su, 16, 64);
    su += __shfl_xor(su, 32, 64);
    const float rs = 1.0f / su;
#pragma unroll
    for (int fk = 0; fk < 8; ++fk){
      const int kk = fk * 16 + lhi * 4;
      unsigned lo = (unsigned)f2b(st[fk][fq][0] * rs) | ((unsigned)f2b(st[fk][fq][1] * rs) << 16);
      unsigned hi = (unsigned)f2b(st[fk][fq][2] * rs) | ((unsigned)f2b(st[fk][fq][3] * rs) << 16);
      *(uint2*)((char*)P + qg * 256 + ((kk * 2) ^ ((qg & 7) << 4))) = make_uint2(lo, hi);
    }
  }
  __syncthreads();

  f32x4 oacc[2][4];
#pragma unroll
  for (int i = 0; i < 2; ++i)
#pragma unroll
    for (int j = 0; j < 4; ++j) oacc[i][j] = f32x4{0.f,0.f,0.f,0.f};
#pragma unroll
  for (int ks = 0; ks < 4; ++ks){
    short8 pa[2];
#pragma unroll
    for (int fq = 0; fq < 2; ++fq){
      const int qr = qbase + fq * 16 + llo;
      pa[fq] = *(const short8*)((const char*)P + qr * 256 + ((ks * 64 + lhi * 16) ^ ((qr & 7) << 4)));
    }
#pragma unroll
    for (int fd = 0; fd < 4; ++fd){
      const int dr = fd * 16 + llo;
      short8 vb = *(const short8*)((const char*)Vt + dr * 256 + ((ks * 64 + lhi * 16) ^ ((dr & 7) << 4)));
      oacc[0][fd] = __builtin_amdgcn_mfma_f32_16x16x32_bf16(pa[0], vb, oacc[0][fd], 0, 0, 0);
      oacc[1][fd] = __builtin_amdgcn_mfma_f32_16x16x32_bf16(pa[1], vb, oacc[1][fd], 0, 0, 0);
    }
  }

#pragma unroll
  for (int fq = 0; fq < 2; ++fq)
#pragma unroll
    for (int fd = 0; fd < 4; ++fd)
#pragma unroll
      for (int rr = 0; rr < 4; ++rr){
        const int qg = qbase + fq * 16 + lhi * 4 + rr;
        const int d = fd * 16 + llo;
        const size_t ob = ((size_t)((b * 128 + qg) * 16 + s)) * 768 + h * 64 + d;
        o[ob] = f2b(oacc[fq][fd][rr]);
      }
}

__global__ __launch_bounds__(256) void sentinel_k(float* out){
  if (blockIdx.x == 0 && threadIdx.x == 0) out[0] = 12345.0f;
}

// ---------------- launch ----------------
extern "C" void kernel_launch(void* const* d_in, const int* in_sizes, int n_in,
                              void* d_out, int out_size, void* d_ws, size_t ws_size,
                              hipStream_t stream){
  const float* x       = (const float*)d_in[0];
  const float* sn_g    = (const float*)d_in[2];
  const float* sn_b    = (const float*)d_in[3];
  const float* sa_in_w = (const float*)d_in[4];
  const float* sa_in_b = (const float*)d_in[5];
  const float* sa_out_w= (const float*)d_in[6];
  const float* sa_out_b= (const float*)d_in[7];
  const float* tn_g    = (const float*)d_in[8];
  const float* tn_b    = (const float*)d_in[9];
  const float* tq_w    = (const float*)d_in[10];
  const float* tq_b    = (const float*)d_in[11];
  const float* tk_w    = (const float*)d_in[12];
  const float* tk_b    = (const float*)d_in[13];
  const float* tv_w    = (const float*)d_in[14];
  const float* tv_b    = (const float*)d_in[15];
  const float* to_w    = (const float*)d_in[16];
  const float* to_b    = (const float*)d_in[17];
  const float* fn_g    = (const float*)d_in[18];
  const float* fn_b    = (const float*)d_in[19];
  const float* f1_w    = (const float*)d_in[20];
  const float* f1_b    = (const float*)d_in[21];
  const float* f2_w    = (const float*)d_in[22];
  const float* f2_b    = (const float*)d_in[23];

  char* ws = (char*)d_ws;
  size_t off = 0;
  auto alloc = [&](size_t bytes) -> void* {
    void* p = ws + off;
    off += (bytes + 255) & ~(size_t)255;
    return p;
  };
  unsigned short* Wqkv = (unsigned short*)alloc((size_t)2304*768*2);
  unsigned short* Wo1  = (unsigned short*)alloc((size_t)768*768*2);
  unsigned short* W3   = (unsigned short*)alloc((size_t)2304*768*2);
  float*          b3   = (float*)alloc(2304*4);
  unsigned short* Wto  = (unsigned short*)alloc((size_t)768*768*2);
  unsigned short* Wf1  = (unsigned short*)alloc((size_t)3072*768*2);
  unsigned short* Wf2  = (unsigned short*)alloc((size_t)768*3072*2);
  float*          rope = (float*)alloc(128*32*2*4);
  unsigned short* xn   = (unsigned short*)alloc((size_t)NTOK*768*2);
  unsigned short* qkv  = (unsigned short*)alloc((size_t)NTOK*3072*2);
  unsigned short* xs2  = (unsigned short*)alloc((size_t)NTOK*768*2);
  unsigned short* xt2  = (unsigned short*)alloc((size_t)NTOK*768*2);
  unsigned short* ob   = xn; // alias: xn dead when attn output written

  if (ws_size < off){ sentinel_k<<<1, 64, 0, stream>>>((float*)d_out); return; }

  convert_k<<<1024, 256, 0, stream>>>(sa_in_w, Wqkv, 2304*768/4);
  convert_k<<<512, 256, 0, stream>>>(sa_out_w, Wo1, 768*768/4);
  convert_k<<<512, 256, 0, stream>>>(tq_w, W3, 768*768/4);
  convert_k<<<512, 256, 0, stream>>>(tk_w, W3 + 768*768, 768*768/4);
  convert_k<<<512, 256, 0, stream>>>(tv_w, W3 + 2*768*768, 768*768/4);
  concat3_k<<<3, 256, 0, stream>>>(tq_b, tk_b, tv_b, b3);
  convert_k<<<512, 256, 0, stream>>>(to_w, Wto, 768*768/4);
  convert_k<<<1024, 256, 0, stream>>>(f1_w, Wf1, 3072*768/4);
  convert_k<<<1024, 256, 0, stream>>>(f2_w, Wf2, 768*3072/4);
  rope_k<<<16, 256, 0, stream>>>(rope);

  // spatial block
  ln_k<1><<<NTOK, 256, 0, stream>>>(x, sn_g, sn_b, xn);
  gemm256_k<0,4><<<dim3(9, 256), 512, 0, stream>>>(xn, Wqkv, sa_in_b, nullptr, qkv, 768, 2304);
  sattn_k<<<dim3(2048, 12), 256, 0, stream>>>(qkv, ob);
  gemm256_k<2,4><<<dim3(3, 256), 512, 0, stream>>>(ob, Wo1, sa_out_b, x, xs2, 768, 768);

  // temporal block
  ln_k<0><<<NTOK, 256, 0, stream>>>(xs2, tn_g, tn_b, xn);
  gemm256_k<0,4><<<dim3(9, 256), 512, 0, stream>>>(xn, W3, b3, nullptr, qkv, 768, 2304);
  tattn_k<<<dim3(256, 12), 256, 0, stream>>>(qkv, rope, ob);
  gemm256_k<3,4><<<dim3(3, 256), 512, 0, stream>>>(ob, Wto, to_b, xs2, xt2, 768, 768);

  // FFN
  ln_k<0><<<NTOK, 256, 0, stream>>>(xt2, fn_g, fn_b, xn);
  gemm256_k<1,8><<<dim3(12, 128), 512, 0, stream>>>(xn, Wf1, f1_b, nullptr, qkv, 768, 3072);
  gemm256_k<4,4><<<dim3(3, 256), 512, 0, stream>>>(qkv, Wf2, f2_b, xt2, d_out, 3072, 768);
}